// Round 10
// baseline (335.381 us; speedup 1.0000x reference)
//
#include <hip/hip_runtime.h>
#include <cstdint>

#define NBOX 25200
#define NCLS 80
#define NIMG 16
#define KPRE 256
#define MAXB 100
#define SCORE_THR 0.25f
#define IOU_THR 0.1f
#define GCAP 512
#define GCAP_OLD 2048
#define NBINS_OLD 4096
#define FK 512
#define LCAP 3072
#define SCAP 24                      /* per-(block,class) staging cap */
#define CSTR 16                      /* cnts stride in u32 (64B line pad) */
#define CUT 0.5f
#define BINW 0.001953125f            /* (1-CUT)/256 exact */
#define HS2 512.0f                   /* 256/(1-CUT) */
#define RSC 262144.0f                /* 512/BINW */
#define BPI 394                      /* blocks per image: 19 + 75 + 300 */
#define FBBINS 2048                  /* fallback/final hist bins (8 KB overlay) */

__constant__ float c_AW[9] = {10.f,16.f,33.f,30.f,62.f,59.f,116.f,156.f,373.f};
__constant__ float c_AH[9] = {13.f,30.f,23.f,61.f,45.f,119.f,90.f,198.f,326.f};

__device__ __forceinline__ float sigmoidf_(float x) { return 1.0f / (1.0f + expf(-x)); }

__device__ __forceinline__ void box_loc(int i, const float* p5, const float* p4, const float* p3,
                                        const float*& p, int& g, int& li, int& abase) {
  if (i < 1200)      { p = p5; g = 20; li = i;        abase = 6; }
  else if (i < 6000) { p = p4; g = 40; li = i - 1200; abase = 3; }
  else               { p = p3; g = 80; li = i - 6000; abase = 0; }
}

// exact ref-rounding score recomputed from raw logits (fallback paths only)
__device__ __forceinline__ float score_full(const float* p5, const float* p4, const float* p3,
                                            int b, int c, int i) {
  const float* p; int g, li, abase;
  box_loc(i, p5, p4, p3, p, g, li, abase);
  const float* f = p + (size_t)((size_t)b * g * g * 3 + li) * 85;
  return __fmul_rn(sigmoidf_(f[4]), sigmoidf_(f[5 + c]));
}

// exact ref-rounding box recomputed from raw logits (identical ops to reference)
__device__ __forceinline__ float4 decode_box(const float* p5, const float* p4, const float* p3,
                                             int b, int i) {
  const float* p; int g, li, abase;
  box_loc(i, p5, p4, p3, p, g, li, abase);
  const float* f = p + (size_t)((size_t)b * g * g * 3 + li) * 85;
  int cell = li / 3, a = li - cell * 3;
  float ratio = 640.0f / (float)g;
  float cx = (sigmoidf_(f[0]) + (float)(cell % g)) * ratio;
  float cy = (sigmoidf_(f[1]) + (float)(cell / g)) * ratio;
  float w = expf(f[2]) * c_AW[abase + a];
  float h = expf(f[3]) * c_AH[abase + a];
  float hw = 0.5f * w, hh = 0.5f * h;
  return make_float4(cx - hw, cy - hh, cx + hw, cy + hh);
}

// ============ Kernel A: candidate scan only (boxes recomputed downstream) ============
__global__ __launch_bounds__(512) void decode_push_kernel(
    const float* __restrict__ p5, const float* __restrict__ p4, const float* __restrict__ p3,
    unsigned long long* __restrict__ lists, uint32_t* __restrict__ cnts,
    uint32_t* __restrict__ ovfl)
{
  __shared__ float rec[64 * 85];                   // 21.76 KB: 64 contiguous records
  __shared__ unsigned long long slist[NCLS][SCAP]; // 15.36 KB staging
  __shared__ uint32_t wcnt[NCLS];
  __shared__ uint32_t sbase[NCLS], sst[NCLS];
  __shared__ unsigned short pairbuf[8 * 64];       // 1 KB: per-wave survivor pairs

  const int bi = blockIdx.x;
  const int b = bi / BPI, r = bi - b * BPI;
  const float* p; int g, lb, s0, nb;
  if (r < 19)      { p = p5; g = 20; lb = 0;    s0 = r * 64;        nb = 1200  - s0; }
  else if (r < 94) { p = p4; g = 40; lb = 1200; s0 = (r - 19) * 64; nb = 4800  - s0; }
  else             { p = p3; g = 80; lb = 6000; s0 = (r - 94) * 64; nb = 19200 - s0; }
  if (nb > 64) nb = 64;
  const int tid = threadIdx.x;

  if (tid < NCLS) wcnt[tid] = 0;
  {
    const float4* src4 = (const float4*)(p + ((size_t)b * g * g * 3 + s0) * 85);
    float4* rec4 = (float4*)rec;
    int n4 = nb * 85 / 4;
    for (int k = tid; k < n4; k += 512) rec4[k] = src4[k];
  }
  __syncthreads();

  // class scan: wave w owns classes [10w, 10w+10); logit-threshold prune,
  // wave-compacted survivors, dense exact-sigmoid flush (candidate set exact).
  {
    const int wave = tid >> 6, lane = tid & 63;
    const int c0 = wave * 10;
    const bool jok = lane < nb;
    float cl = jok ? rec[lane * 85 + 4] : -1.0f;   // conf logit
    float Lthr;
    if (!jok || cl <= 0.0f) {
      Lthr = 3.0e38f;                              // conf <= 0.5 -> s < 0.5 always
    } else {
      float conf = 1.0f / (1.0f + expf(-cl));
      float u2 = CUT / conf;                       // (0.5, 1)
      if (u2 > 0.999f) Lthr = -3.0e38f;            // near-boundary conf: exact all classes
      else Lthr = logf(u2 / (1.0f - u2)) - 0.01f;  // margin >> fp error of L
    }
    const float* fl = rec + lane * 85 + 5;
    const unsigned long long lt = (lane == 0) ? 0ull : (~0ull >> (64 - lane));
    unsigned short* pb = pairbuf + (wave << 6);

    auto flushFn = [&](int mm) {
      if (lane < mm) {
        int e = pb[lane];
        int l2 = e >> 4, cc2 = e & 15;
        int c2 = c0 + cc2;
        float s = __fmul_rn(sigmoidf_(rec[l2 * 85 + 4]), sigmoidf_(rec[l2 * 85 + 5 + c2]));
        if (s > CUT) {
          uint32_t slot = atomicAdd(&wcnt[c2], 1u);
          if (slot < SCAP)
            slist[c2][slot] = ((unsigned long long)__float_as_uint(s) << 32)
                              | (0xFFFFFFFFu - (uint32_t)(lb + s0 + l2));
        }
      }
    };

    int m = 0;
    for (int cc = 0; cc < 10; ++cc) {
      float lg = jok ? fl[c0 + cc] : -3.0e38f;
      bool cand = lg > Lthr;
      unsigned long long mk = __ballot(cand);
      int pc = __popcll(mk);
      if (m + pc > 64) { flushFn(m); m = 0; }
      if (cand) {
        int rank = __popcll(mk & lt);
        pb[m + rank] = (unsigned short)((lane << 4) | cc);
      }
      m += pc;
    }
    flushFn(m);
  }
  __syncthreads();

  if (tid < NCLS) {
    uint32_t full = wcnt[tid];
    if (full > SCAP) ovfl[b * NCLS + tid] = 1u;
    uint32_t st = full < SCAP ? full : SCAP;
    sst[tid] = st;
    sbase[tid] = atomicAdd(&cnts[(size_t)(b * NCLS + tid) * CSTR], st);
  }
  __syncthreads();

  for (int t = tid; t < NCLS * SCAP; t += 512) {
    int c = t / SCAP, k = t - c * SCAP;
    if ((uint32_t)k < sst[c]) {
      uint32_t dst = sbase[c] + (uint32_t)k;
      if (dst < LCAP)
        lists[(size_t)(b * NCLS + c) * LCAP + dst] = slist[c][k];
    }
  }
}

// ============ Kernel B: select + sort + wave-scan bitmask NMS + fused per-image final ============
union ShMix2 {
  uint32_t rhist[512];                  // refine hist (2 KB)
  uint32_t fhist[FBBINS];               // fallback/final hist (8 KB)
  unsigned long long rowm[KPRE][4];     // IoU adjacency rows (8 KB)
};

__global__ __launch_bounds__(512) void select_nms_list_kernel(
    const unsigned long long* __restrict__ lists, const uint32_t* __restrict__ cnts,
    const uint32_t* __restrict__ ovfl,
    const float* __restrict__ p5, const float* __restrict__ p4, const float* __restrict__ p3,
    float* __restrict__ kept_s, int* __restrict__ top_i,
    uint32_t* __restrict__ imgcnt, float* __restrict__ out)
{
  const int task = blockIdx.x;
  const int b = task / NCLS, c = task - b * NCLS;
  const int tid = threadIdx.x;

  __shared__ uint32_t S[256];
  __shared__ unsigned long long keys[GCAP];      // 4 KB
  __shared__ ShMix2 u;                           // 8 KB
  __shared__ float4 bbx[KPRE];                   // 4 KB
  __shared__ float bar_[KPRE];                   // 1 KB
  __shared__ unsigned long long suppInit[4];
  __shared__ unsigned long long sh_t[4];
  __shared__ int s_B, s_cnt, s_state, sh_stop, sh_last;
  __shared__ float s_gl, s_lo, s_hi;
  __shared__ uint32_t s_above, s_g2;

  const uint32_t cntraw = cnts[(size_t)task * CSTR];
  bool fb = (ovfl[task] != 0u) || !(cntraw >= (uint32_t)KPRE && cntraw <= (uint32_t)LCAP);
  float thr = CUT;
  int n_all = (int)(cntraw < (uint32_t)LCAP ? cntraw : (uint32_t)LCAP);
  const unsigned long long* gl = lists + (size_t)task * LCAP;

  if (!fb && n_all > 500) {
    if (tid < 256) S[tid] = 0;
    __syncthreads();
    for (int z = tid; z < n_all; z += 512) {
      float s = __uint_as_float((uint32_t)(gl[z] >> 32));
      int bin = (int)(__fmul_rn(__fsub_rn(s, CUT), HS2));
      bin = bin < 0 ? 0 : (bin > 255 ? 255 : bin);
      atomicAdd(&S[bin], 1u);
    }
    __syncthreads();
    for (int off = 1; off < 256; off <<= 1) {     // suffix scan: S[z] = count(bin >= z)
      uint32_t add = 0;
      if (tid < 256 && tid + off < 256) add = S[tid + off];
      __syncthreads();
      if (tid < 256) S[tid] += add;
      __syncthreads();
    }
    if (tid == 0) s_B = 0;
    __syncthreads();
    if (tid < 256) {
      uint32_t Sz = S[tid];
      uint32_t Sz1 = (tid < 255) ? S[tid + 1] : 0u;
      if (Sz >= KPRE && (tid == 255 || Sz1 < KPRE)) s_B = tid;
    }
    __syncthreads();
    const int B = s_B;
    const uint32_t gcount = S[B];
    const uint32_t aboveB = (B < 255) ? S[B + 1] : 0u;
    thr = CUT + (float)B * BINW;
    if (gcount > 500u) {
      for (int z = tid; z < 512; z += 512) u.rhist[z] = 0u;
      __syncthreads();
      float rLo = thr;
      for (int z = tid; z < n_all; z += 512) {
        float s = __uint_as_float((uint32_t)(gl[z] >> 32));
        int bin = (int)(__fmul_rn(__fsub_rn(s, CUT), HS2));
        bin = bin < 0 ? 0 : (bin > 255 ? 255 : bin);
        if (bin == B) {
          int sub = (int)((s - rLo) * RSC);
          sub = sub < 0 ? 0 : (sub > 511 ? 511 : sub);
          atomicAdd(&u.rhist[sub], 1u);
        }
      }
      __syncthreads();
      if (tid == 0) {
        uint32_t acc = aboveB; int B2 = 0;
        for (int z = 511; z >= 0; --z) {
          acc += u.rhist[z];
          if (acc >= KPRE) { B2 = z; break; }
        }
        s_gl = rLo + (float)B2 * (BINW / 512.0f);
        s_g2 = acc;
      }
      __syncthreads();
      thr = s_gl;
      if (s_g2 > 500u) fb = true;
      __syncthreads();
    }
  }

  if (fb) {
    // exact fallback: iterative strided hist over raw scores (never taken on bench data)
    float lo = SCORE_THR, hi = 1.0f;
    uint32_t above = 0;
    float gl2 = SCORE_THR;
    bool done = false;
    for (int iter = 0; iter < 6 && !done; ++iter) {
      for (int z = tid; z < FBBINS; z += 512) u.fhist[z] = 0u;
      __syncthreads();
      float scale = (float)FBBINS / (hi - lo);
      for (int i = tid; i < NBOX; i += 512) {
        float s = score_full(p5, p4, p3, b, c, i);
        if (s > lo && s <= hi) {
          int bin = (int)((s - lo) * scale);
          bin = bin < 0 ? 0 : (bin > FBBINS - 1 ? FBBINS - 1 : bin);
          atomicAdd(&u.fhist[bin], 1u);
        }
      }
      __syncthreads();
      if (tid < 256) {
        uint32_t cs = 0; int base = tid * 8;
        #pragma unroll
        for (int z = 0; z < 8; ++z) cs += u.fhist[base + z];
        S[tid] = cs;
      }
      __syncthreads();
      if (tid == 0) {
        uint32_t acc = 0; int ch;
        for (ch = 255; ch >= 0; --ch) {
          if (above + acc + S[ch] >= KPRE) break;
          acc += S[ch];
        }
        if (ch < 0) { s_state = 1; s_gl = SCORE_THR; }
        else {
          int B = -1;
          for (int z = ch * 8 + 7; z >= ch * 8; --z) {
            acc += u.fhist[z];
            if (above + acc >= KPRE) { B = z; break; }
          }
          uint32_t popB = u.fhist[B];
          uint32_t aboveNew = above + acc - popB;
          float wdt = (hi - lo) / (float)FBBINS;
          float binLo = lo + (float)B * wdt;
          if (aboveNew + popB <= 496u || iter == 5) { s_state = 1; s_gl = binLo; }
          else { s_state = 0; s_lo = binLo; s_hi = binLo + wdt; s_above = aboveNew; }
        }
      }
      __syncthreads();
      if (s_state == 1) { gl2 = s_gl; done = true; }
      else { lo = s_lo; hi = s_hi; above = s_above; }
      __syncthreads();
    }
    thr = gl2;
  }

  float thr_n = __uint_as_float(__float_as_uint(thr) - 8u);   // ulp nudge vs bin rounding

  if (tid == 0) s_cnt = 0;
  __syncthreads();
  if (!fb) {
    for (int z = tid; z < n_all; z += 512) {
      unsigned long long kk = gl[z];
      float s = __uint_as_float((uint32_t)(kk >> 32));
      if (s > thr_n) {
        int slot = atomicAdd(&s_cnt, 1);
        if (slot < GCAP) keys[slot] = kk;
      }
    }
  } else {
    for (int i = tid; i < NBOX; i += 512) {
      float s = score_full(p5, p4, p3, b, c, i);
      if (s > thr_n && s > SCORE_THR) {
        int slot = atomicAdd(&s_cnt, 1);
        if (slot < GCAP)
          keys[slot] = ((unsigned long long)__float_as_uint(s) << 32) | (0xFFFFFFFFu - (uint32_t)i);
      }
    }
  }
  __syncthreads();
  int n = s_cnt < GCAP ? s_cnt : GCAP;
  if (tid >= n) keys[tid] = 0ull;
  __syncthreads();
  // hybrid bitonic sort 512 descending: j<64 via register shfl_xor, j>=64 via LDS
  {
    unsigned long long v = keys[tid];
    for (int k = 2; k <= GCAP; k <<= 1) {
      for (int j = k >> 1; j > 0; j >>= 1) {
        unsigned long long pv;
        if (j >= 64) {
          keys[tid] = v;
          __syncthreads();
          pv = keys[tid ^ j];
          __syncthreads();
        } else {
          pv = __shfl_xor(v, j, 64);
        }
        bool takeMax = (((tid & k) == 0) == ((tid & j) == 0));
        v = takeMax ? (v > pv ? v : pv) : (v < pv ? v : pv);
      }
    }
    keys[tid] = v;
  }
  __syncthreads();

  // ---- chunked bitmask NMS on top-256, wave-register suppression scan ----
  const int col = tid & 255;
  float sc; int idx;
  {
    unsigned long long kk = keys[col];
    if ((uint32_t)(kk >> 32) != 0u) { sc = __uint_as_float((uint32_t)(kk >> 32)); idx = (int)(0xFFFFFFFFu - (uint32_t)kk); }
    else { sc = -1.0f; idx = 0; }
  }
  if (tid < KPRE) {
    float4 bx = decode_box(p5, p4, p3, b, idx);
    bbx[tid] = bx;
    bar_[tid] = __fmul_rn(fmaxf(__fsub_rn(bx.z, bx.x), 0.0f), fmaxf(__fsub_rn(bx.w, bx.y), 0.0f));
  }
  {
    unsigned long long alive = __ballot(sc > SCORE_THR);
    if (tid < KPRE && (tid & 63) == 0) suppInit[tid >> 6] = ~alive;
  }
  if (tid == 0) sh_stop = 0;
  __syncthreads();
  float4 MB = bbx[col];
  float x1 = MB.x, y1 = MB.y, x2 = MB.z, y2 = MB.w;
  float area = bar_[col];
  if (tid < 4) sh_t[tid] = suppInit[tid];
  __syncthreads();

  int P = 4;
  const int rg = tid >> 8;                       // row-group: 0 or 1
  #pragma unroll
  for (int q = 0; q < 4; ++q) {
    for (int ii = 0; ii < 64; ii += 2) {
      int i = q * 64 + ii + rg;
      if (!((sh_t[q] >> (ii + rg)) & 1ull)) {
        float4 B = bbx[i];
        float ar = bar_[i];
        float iw = fmaxf(__fsub_rn(fminf(x2, B.z), fmaxf(x1, B.x)), 0.0f);
        float ih = fmaxf(__fsub_rn(fminf(y2, B.w), fmaxf(y1, B.y)), 0.0f);
        float inter = __fmul_rn(iw, ih);
        float ab = __fadd_rn(ar, area);
        float diff = __fsub_rn(__fmul_rn(inter, 1.1f), __fmul_rn(0.1f, ab));
        bool sup;
        if (fabsf(diff) > 1e-5f * ab) {
          sup = diff > 0.0f;
        } else {
          float uni = __fsub_rn(ab, inter);
          sup = (inter / fmaxf(uni, 1e-9f)) > IOU_THR;
        }
        sup = sup && (col > i);
        unsigned long long m = __ballot(sup);
        if ((tid & 63) == 0) u.rowm[i][(tid >> 6) & 3] = m;
      }
    }
    __syncthreads();
    if (tid < 64) {                              // wave-register serial scan (uniform branches)
      unsigned long long r0 = u.rowm[q * 64 + tid][0];
      unsigned long long r1 = u.rowm[q * 64 + tid][1];
      unsigned long long r2 = u.rowm[q * 64 + tid][2];
      unsigned long long r3 = u.rowm[q * 64 + tid][3];
      unsigned long long t0 = sh_t[0], t1 = sh_t[1], t2 = sh_t[2], t3 = sh_t[3];
      unsigned long long tq = (q == 0) ? t0 : (q == 1) ? t1 : (q == 2) ? t2 : t3;
      for (int ii = 0; ii < 64; ++ii) {
        if (!((tq >> ii) & 1ull)) {
          t0 |= __shfl(r0, ii); t1 |= __shfl(r1, ii);
          t2 |= __shfl(r2, ii); t3 |= __shfl(r3, ii);
          tq = (q == 0) ? t0 : (q == 1) ? t1 : (q == 2) ? t2 : t3;
        }
      }
      if (tid == 0) {
        sh_t[0] = t0; sh_t[1] = t1; sh_t[2] = t2; sh_t[3] = t3;
        int kept = __popcll(~t0);
        if (q >= 1) kept += __popcll(~t1);
        if (q >= 2) kept += __popcll(~t2);
        if (q >= 3) kept += __popcll(~t3);
        if (kept >= MAXB) sh_stop = 1;           // rows beyond can't enter the top-100
      }
    }
    __syncthreads();
    if (sh_stop) { P = q + 1; break; }
  }

  if (tid < KPRE) {
    unsigned long long tw = sh_t[tid >> 6];
    bool kept = (tid < 64 * P) && !((tw >> (tid & 63)) & 1ull);
    int rank = 0;
    #pragma unroll
    for (int w2 = 0; w2 < 4; ++w2)
      if (w2 < (tid >> 6)) rank += __popcll(~sh_t[w2]);
    int l = tid & 63;
    rank += (l == 0) ? 0 : __popcll(~tw & ((~0ull) >> (64 - l)));
    bool fin = kept && (rank < MAXB);
    kept_s[(size_t)task * KPRE + tid] = fin ? sc : -1.0f;
    top_i[(size_t)task * KPRE + tid] = idx;
  }

  // ---- fused per-image final top-100 (last-finishing block of image b) ----
  __threadfence();                               // release own kept_s/top_i writes (all threads)
  __syncthreads();
  if (tid == 0) {
    uint32_t done = atomicAdd(&imgcnt[b], 1u);
    sh_last = (done == (uint32_t)(NCLS - 1)) ? 1 : 0;
  }
  __syncthreads();
  if (!sh_last) return;
  __threadfence();                               // acquire other blocks' writes

  const float* ks = kept_s + (size_t)b * NCLS * KPRE;
  const int NK = NCLS * KPRE;
  {
    float lo = SCORE_THR, hi = 1.0f;
    uint32_t above = 0;
    float gLo = SCORE_THR;
    bool done2 = false;
    for (int iter = 0; iter < 4 && !done2; ++iter) {
      for (int z = tid; z < FBBINS; z += 512) u.fhist[z] = 0u;
      __syncthreads();
      float scale = (float)FBBINS / (hi - lo);
      for (int z = tid; z < NK; z += 512) {
        float s = ks[z];
        if (s > lo && s <= hi) {
          int bin = (int)((s - lo) * scale);
          bin = bin < 0 ? 0 : (bin > FBBINS - 1 ? FBBINS - 1 : bin);
          atomicAdd(&u.fhist[bin], 1u);
        }
      }
      __syncthreads();
      if (tid < 256) {
        uint32_t cs = 0; int base = tid * 8;
        #pragma unroll
        for (int z = 0; z < 8; ++z) cs += u.fhist[base + z];
        S[tid] = cs;
      }
      __syncthreads();
      if (tid == 0) {
        uint32_t acc = 0; int ch;
        for (ch = 255; ch >= 0; --ch) {
          if (above + acc + S[ch] >= MAXB) break;
          acc += S[ch];
        }
        if (ch < 0) { s_state = 1; s_gl = SCORE_THR; }   // <100 positives: take all
        else {
          int B = -1;
          for (int z = ch * 8 + 7; z >= ch * 8; --z) {
            acc += u.fhist[z];
            if (above + acc >= MAXB) { B = z; break; }
          }
          uint32_t popB = u.fhist[B];
          uint32_t aboveNew = above + acc - popB;
          float wdt = (hi - lo) / (float)FBBINS;
          float binLo = lo + (float)B * wdt;
          if (aboveNew + popB <= (uint32_t)(FK - 64) || iter == 3) { s_state = 1; s_gl = binLo; }
          else { s_state = 0; s_lo = binLo; s_hi = binLo + wdt; s_above = aboveNew; }
        }
      }
      __syncthreads();
      if (s_state == 1) { gLo = s_gl; done2 = true; }
      else { lo = s_lo; hi = s_hi; above = s_above; }
      __syncthreads();
    }
    float gLo_n = __uint_as_float(__float_as_uint(gLo) - 8u);

    if (tid == 0) s_cnt = 0;
    __syncthreads();
    for (int z = tid; z < NK; z += 512) {
      float s = ks[z];
      if (s > gLo_n && s > 0.0f) {
        int slot = atomicAdd(&s_cnt, 1);
        if (slot < FK)
          keys[slot] = ((unsigned long long)__float_as_uint(s) << 32) | (uint32_t)(0xFFFFFFFFu - (uint32_t)z);
      }
    }
    __syncthreads();
    int n2 = s_cnt < FK ? s_cnt : FK;
    if (tid >= n2) keys[tid] = 0ull;
    __syncthreads();
    {
      unsigned long long v = keys[tid];
      for (int k = 2; k <= FK; k <<= 1) {
        for (int j = k >> 1; j > 0; j >>= 1) {
          unsigned long long pv;
          if (j >= 64) {
            keys[tid] = v;
            __syncthreads();
            pv = keys[tid ^ j];
            __syncthreads();
          } else {
            pv = __shfl_xor(v, j, 64);
          }
          bool takeMax = (((tid & k) == 0) == ((tid & j) == 0));
          v = takeMax ? (v > pv ? v : pv) : (v < pv ? v : pv);
        }
      }
      keys[tid] = v;
    }
    __syncthreads();
    float* ob = out + (size_t)b * MAXB * 4;
    float* os = out + (size_t)NIMG * MAXB * 4 + (size_t)b * MAXB;
    float* ol = out + (size_t)NIMG * MAXB * 4 + (size_t)NIMG * MAXB + (size_t)b * MAXB;
    for (int t = tid; t < MAXB; t += 512) {
      unsigned long long kk = keys[t];
      if ((uint32_t)(kk >> 32) != 0u) {
        float s = __uint_as_float((uint32_t)(kk >> 32));
        int fr = (int)(0xFFFFFFFFu - (uint32_t)kk);     // c*256 + r (class-major flat order)
        int cc = fr >> 8, rr = fr & 255;
        int bidx = top_i[((size_t)b * NCLS + cc) * KPRE + rr];
        float4 bx = decode_box(p5, p4, p3, b, bidx);
        ob[t * 4 + 0] = bx.x; ob[t * 4 + 1] = bx.y; ob[t * 4 + 2] = bx.z; ob[t * 4 + 3] = bx.w;
        os[t] = s; ol[t] = (float)cc;
      } else {
        ob[t * 4 + 0] = -1.0f; ob[t * 4 + 1] = -1.0f; ob[t * 4 + 2] = -1.0f; ob[t * 4 + 3] = -1.0f;
        os[t] = -1.0f; ol[t] = -1.0f;
      }
    }
  }
}

// ============ Small-ws fallback path (round-0/1, validated, 256 thr) ============
__global__ __launch_bounds__(256) void decode_kernel(
    const float* __restrict__ p5, const float* __restrict__ p4, const float* __restrict__ p3,
    float* __restrict__ boxes, float* __restrict__ conf)
{
  int t = blockIdx.x * 256 + threadIdx.x;
  if (t >= NIMG * NBOX) return;
  int b = t / NBOX, i = t - b * NBOX;
  float4 bx = decode_box(p5, p4, p3, b, i);
  float* ob = boxes + (size_t)t * 4;
  ob[0] = bx.x; ob[1] = bx.y; ob[2] = bx.z; ob[3] = bx.w;
  const float* p; int g, li, abase;
  box_loc(i, p5, p4, p3, p, g, li, abase);
  conf[t] = sigmoidf_(p[(size_t)((size_t)b * g * g * 3 + li) * 85 + 4]);
}

__device__ __forceinline__ float score_at(
    const float* __restrict__ p5, const float* __restrict__ p4, const float* __restrict__ p3,
    const float* __restrict__ conf, int b, int c, int i)
{
  const float* p; int g, li, abase;
  box_loc(i, p5, p4, p3, p, g, li, abase);
  float logit = p[(size_t)((size_t)b * g * g * 3 + li) * 85 + 5 + c];
  return __fmul_rn(conf[b * NBOX + i], 1.0f / (1.0f + expf(-logit)));
}

__global__ __launch_bounds__(256) void select_nms_kernel(
    const float* __restrict__ p5, const float* __restrict__ p4, const float* __restrict__ p3,
    const float* __restrict__ conf, const float* __restrict__ boxes,
    float* __restrict__ kept_s, int* __restrict__ top_i)
{
  const int task = blockIdx.x;
  const int b = task / NCLS, c = task - b * NCLS;
  const int tid = threadIdx.x;
  __shared__ uint32_t hist[NBINS_OLD];
  __shared__ uint32_t chunkS[256];
  __shared__ unsigned long long keys[GCAP_OLD];
  __shared__ float s_lo, s_hi, s_glo;
  __shared__ uint32_t s_above;
  __shared__ int s_state, s_cnt;

  float lo = SCORE_THR, hi = 1.0f;
  uint32_t above = 0;
  float gatherLo = SCORE_THR;
  bool done = false;
  for (int iter = 0; iter < 6 && !done; ++iter) {
    for (int z = tid; z < NBINS_OLD; z += 256) hist[z] = 0;
    __syncthreads();
    float scale = (float)NBINS_OLD / (hi - lo);
    for (int i = tid; i < NBOX; i += 256) {
      float s = score_at(p5, p4, p3, conf, b, c, i);
      if (s > lo && s <= hi) {
        int bin = (int)((s - lo) * scale);
        bin = bin < 0 ? 0 : (bin > NBINS_OLD - 1 ? NBINS_OLD - 1 : bin);
        atomicAdd(&hist[bin], 1u);
      }
    }
    __syncthreads();
    { uint32_t cs = 0; int base = tid * 16;
      #pragma unroll
      for (int z = 0; z < 16; ++z) cs += hist[base + z];
      chunkS[tid] = cs; }
    __syncthreads();
    if (tid == 0) {
      uint32_t acc = 0; int ch;
      for (ch = 255; ch >= 0; --ch) {
        if (above + acc + chunkS[ch] >= KPRE) break;
        acc += chunkS[ch];
      }
      if (ch < 0) { s_state = 1; s_glo = SCORE_THR; }
      else {
        int B = -1;
        for (int z = ch * 16 + 15; z >= ch * 16; --z) {
          acc += hist[z];
          if (above + acc >= KPRE) { B = z; break; }
        }
        uint32_t popB = hist[B];
        uint32_t aboveNew = above + acc - popB;
        float wdt = (hi - lo) / (float)NBINS_OLD;
        float binLo = lo + (float)B * wdt;
        if (aboveNew + popB <= 1024u || iter == 5) { s_state = 1; s_glo = binLo; }
        else { s_state = 0; s_lo = binLo; s_hi = binLo + wdt; s_above = aboveNew; }
      }
    }
    __syncthreads();
    if (s_state == 1) { gatherLo = s_glo; done = true; }
    else { lo = s_lo; hi = s_hi; above = s_above; }
    __syncthreads();
  }
  gatherLo = __uint_as_float(__float_as_uint(gatherLo) - 8u);
  if (tid == 0) s_cnt = 0;
  __syncthreads();
  for (int i = tid; i < NBOX; i += 256) {
    float s = score_at(p5, p4, p3, conf, b, c, i);
    if (s > gatherLo && s > SCORE_THR) {
      int slot = atomicAdd(&s_cnt, 1);
      if (slot < GCAP_OLD)
        keys[slot] = ((unsigned long long)__float_as_uint(s) << 32) | (uint32_t)(0xFFFFFFFFu - (uint32_t)i);
    }
  }
  __syncthreads();
  int n = s_cnt < GCAP_OLD ? s_cnt : GCAP_OLD;
  for (int z = tid; z < GCAP_OLD; z += 256) if (z >= n) keys[z] = 0ull;
  __syncthreads();
  for (int k = 2; k <= GCAP_OLD; k <<= 1) {
    for (int j = k >> 1; j > 0; j >>= 1) {
      for (int i2 = tid; i2 < GCAP_OLD; i2 += 256) {
        int ixj = i2 ^ j;
        if (ixj > i2) {
          unsigned long long a0 = keys[i2], b0_ = keys[ixj];
          bool sw = ((i2 & k) == 0) ? (a0 < b0_) : (a0 > b0_);
          if (sw) { keys[i2] = b0_; keys[ixj] = a0; }
        }
      }
      __syncthreads();
    }
  }
  __shared__ float bx1[KPRE], by1[KPRE], bx2[KPRE], by2[KPRE], bar_[KPRE], tsc[KPRE];
  __shared__ int tix[KPRE];
  __shared__ unsigned char suppA[KPRE], keepA[KPRE];
  { int r = tid;
    unsigned long long kk = keys[r];
    float sc; int idx;
    if ((uint32_t)(kk >> 32) != 0u) { sc = __uint_as_float((uint32_t)(kk >> 32)); idx = (int)(0xFFFFFFFFu - (uint32_t)kk); }
    else { sc = -1.0f; idx = 0; }
    tsc[r] = sc; tix[r] = idx;
    const float* bp = boxes + ((size_t)b * NBOX + idx) * 4;
    float x1 = bp[0], y1 = bp[1], x2 = bp[2], y2 = bp[3];
    bx1[r] = x1; by1[r] = y1; bx2[r] = x2; by2[r] = y2;
    bar_[r] = __fmul_rn(fmaxf(__fsub_rn(x2, x1), 0.0f), fmaxf(__fsub_rn(y2, y1), 0.0f));
    suppA[r] = (sc <= SCORE_THR) ? 1 : 0; }
  __syncthreads();
  for (int i = 0; i < KPRE; ++i) {
    if (suppA[i] == 0) {
      int r = tid;
      if (r > i) {
        float iw = fmaxf(__fsub_rn(fminf(bx2[r], bx2[i]), fmaxf(bx1[r], bx1[i])), 0.0f);
        float ih = fmaxf(__fsub_rn(fminf(by2[r], by2[i]), fmaxf(by1[r], by1[i])), 0.0f);
        float inter = __fmul_rn(iw, ih);
        float uni = __fsub_rn(__fadd_rn(bar_[r], bar_[i]), inter);
        float iou = inter / fmaxf(uni, 1e-9f);
        if (iou > IOU_THR) suppA[r] = 1;
      }
    }
    __syncthreads();
  }
  if (tid == 0) {
    int cnt = 0;
    for (int r = 0; r < KPRE; ++r) {
      int kp = (suppA[r] == 0) ? 1 : 0;
      if (kp && cnt < MAXB) cnt++; else kp = 0;
      keepA[r] = (unsigned char)kp;
    }
  }
  __syncthreads();
  { int r = tid;
    kept_s[(size_t)task * KPRE + r] = keepA[r] ? tsc[r] : -1.0f;
    top_i[(size_t)task * KPRE + r] = tix[r]; }
}

// fallback-only final top-100 (boxes recomputed from logits)
__global__ __launch_bounds__(256) void final_topk_kernel(
    const float* __restrict__ kept_s, const int* __restrict__ top_i,
    const float* __restrict__ p5, const float* __restrict__ p4, const float* __restrict__ p3,
    float* __restrict__ out)
{
  int b = blockIdx.x, tid = threadIdx.x;
  __shared__ uint32_t hist[NBINS_OLD];
  __shared__ uint32_t chunkS[256];
  __shared__ unsigned long long keys[FK];
  __shared__ float s_lo, s_hi, s_glo;
  __shared__ uint32_t s_above;
  __shared__ int s_state, s_cnt;
  const float* ks = kept_s + (size_t)b * NCLS * KPRE;
  const int NK = NCLS * KPRE;

  float lo = SCORE_THR, hi = 1.0f;
  uint32_t above = 0;
  float gatherLo = SCORE_THR;
  bool done = false;

  for (int iter = 0; iter < 4 && !done; ++iter) {
    for (int z = tid; z < NBINS_OLD; z += 256) hist[z] = 0;
    __syncthreads();
    float scale = (float)NBINS_OLD / (hi - lo);
    for (int z = tid; z < NK; z += 256) {
      float s = ks[z];
      if (s > lo && s <= hi) {
        int bin = (int)((s - lo) * scale);
        bin = bin < 0 ? 0 : (bin > NBINS_OLD - 1 ? NBINS_OLD - 1 : bin);
        atomicAdd(&hist[bin], 1u);
      }
    }
    __syncthreads();
    {
      uint32_t cs = 0; int base = tid * 16;
      #pragma unroll
      for (int z = 0; z < 16; ++z) cs += hist[base + z];
      chunkS[tid] = cs;
    }
    __syncthreads();
    if (tid == 0) {
      uint32_t acc = 0; int ch;
      for (ch = 255; ch >= 0; --ch) {
        if (above + acc + chunkS[ch] >= MAXB) break;
        acc += chunkS[ch];
      }
      if (ch < 0) { s_state = 1; s_glo = SCORE_THR; }
      else {
        int B = -1;
        for (int z = ch * 16 + 15; z >= ch * 16; --z) {
          acc += hist[z];
          if (above + acc >= MAXB) { B = z; break; }
        }
        uint32_t popB = hist[B];
        uint32_t aboveNew = above + acc - popB;
        float wdt = (hi - lo) / (float)NBINS_OLD;
        float binLo = lo + (float)B * wdt;
        if (aboveNew + popB <= (uint32_t)(FK - 64) || iter == 3) { s_state = 1; s_glo = binLo; }
        else { s_state = 0; s_lo = binLo; s_hi = binLo + wdt; s_above = aboveNew; }
      }
    }
    __syncthreads();
    if (s_state == 1) { gatherLo = s_glo; done = true; }
    else { lo = s_lo; hi = s_hi; above = s_above; }
    __syncthreads();
  }
  gatherLo = __uint_as_float(__float_as_uint(gatherLo) - 8u);

  if (tid == 0) s_cnt = 0;
  __syncthreads();
  for (int z = tid; z < NK; z += 256) {
    float s = ks[z];
    if (s > gatherLo && s > 0.0f) {
      int slot = atomicAdd(&s_cnt, 1);
      if (slot < FK)
        keys[slot] = ((unsigned long long)__float_as_uint(s) << 32) | (uint32_t)(0xFFFFFFFFu - (uint32_t)z);
    }
  }
  __syncthreads();
  int n = s_cnt < FK ? s_cnt : FK;
  for (int z = tid; z < FK; z += 256) if (z >= n) keys[z] = 0ull;
  __syncthreads();
  for (int k = 2; k <= FK; k <<= 1) {
    for (int j = k >> 1; j > 0; j >>= 1) {
      for (int i2 = tid; i2 < FK; i2 += 256) {
        int ixj = i2 ^ j;
        if (ixj > i2) {
          unsigned long long a0 = keys[i2], b0_ = keys[ixj];
          bool sw = ((i2 & k) == 0) ? (a0 < b0_) : (a0 > b0_);
          if (sw) { keys[i2] = b0_; keys[ixj] = a0; }
        }
      }
      __syncthreads();
    }
  }
  float* ob = out + (size_t)b * MAXB * 4;
  float* os = out + (size_t)NIMG * MAXB * 4 + (size_t)b * MAXB;
  float* ol = out + (size_t)NIMG * MAXB * 4 + (size_t)NIMG * MAXB + (size_t)b * MAXB;
  for (int t = tid; t < MAXB; t += 256) {
    unsigned long long kk = keys[t];
    if ((uint32_t)(kk >> 32) != 0u) {
      float s = __uint_as_float((uint32_t)(kk >> 32));
      int fr = (int)(0xFFFFFFFFu - (uint32_t)kk);
      int cc = fr >> 8, rr = fr & 255;
      int idx = top_i[((size_t)b * NCLS + cc) * KPRE + rr];
      float4 bx = decode_box(p5, p4, p3, b, idx);
      ob[t * 4 + 0] = bx.x; ob[t * 4 + 1] = bx.y; ob[t * 4 + 2] = bx.z; ob[t * 4 + 3] = bx.w;
      os[t] = s; ol[t] = (float)cc;
    } else {
      ob[t * 4 + 0] = -1.0f; ob[t * 4 + 1] = -1.0f; ob[t * 4 + 2] = -1.0f; ob[t * 4 + 3] = -1.0f;
      os[t] = -1.0f; ol[t] = -1.0f;
    }
  }
}

extern "C" void kernel_launch(void* const* d_in, const int* in_sizes, int n_in,
                              void* d_out, int out_size, void* d_ws, size_t ws_size,
                              hipStream_t stream)
{
  const float* p5 = (const float*)d_in[0];
  const float* p4 = (const float*)d_in[1];
  const float* p3 = (const float*)d_in[2];
  float* out = (float*)d_out;

  float*    boxes  = (float*)d_ws;                                   // fallback only
  float*    kept   = boxes + (size_t)NIMG * NBOX * 4;                // 1280*256 f
  int*      topi   = (int*)(kept + (size_t)NIMG * NCLS * KPRE);      // 1280*256 i
  uint32_t* cnts   = (uint32_t*)(topi + (size_t)NIMG * NCLS * KPRE); // 1280*16 u32
  uint32_t* ovfl   = cnts + (size_t)NIMG * NCLS * CSTR;              // 1280 u32
  uint32_t* imgcnt = ovfl + NIMG * NCLS;                             // 16 u32
  unsigned long long* lists = (unsigned long long*)(imgcnt + NIMG);  // 1280*3072 u64

  size_t need_main = ((size_t)NIMG * NBOX * 4 + (size_t)NIMG * NCLS * KPRE * 2
                      + (size_t)NIMG * NCLS * CSTR + (size_t)NIMG * NCLS + NIMG) * 4
                     + (size_t)NIMG * NCLS * LCAP * 8;

  if (ws_size >= need_main) {
    hipMemsetAsync(cnts, 0,
                   ((size_t)NIMG * NCLS * CSTR + (size_t)NIMG * NCLS + NIMG) * sizeof(uint32_t),
                   stream);
    decode_push_kernel<<<NIMG * BPI, 512, 0, stream>>>(p5, p4, p3, lists, cnts, ovfl);
    select_nms_list_kernel<<<NIMG * NCLS, 512, 0, stream>>>(lists, cnts, ovfl, p5, p4, p3,
                                                            kept, topi, imgcnt, out);
  } else {
    float* conf = (float*)lists;                                     // overlay (fallback only)
    decode_kernel<<<(NIMG * NBOX + 255) / 256, 256, 0, stream>>>(p5, p4, p3, boxes, conf);
    select_nms_kernel<<<NIMG * NCLS, 256, 0, stream>>>(p5, p4, p3, conf, boxes, kept, topi);
    final_topk_kernel<<<NIMG, 256, 0, stream>>>(kept, topi, p5, p4, p3, out);
  }
}

// Round 11
// 216.692 us; speedup vs baseline: 1.5477x; 1.5477x over previous
//
#include <hip/hip_runtime.h>
#include <cstdint>

#define NBOX 25200
#define NCLS 80
#define NIMG 16
#define KPRE 256
#define MAXB 100
#define SCORE_THR 0.25f
#define IOU_THR 0.1f
#define GCAP 512
#define GCAP_OLD 2048
#define NBINS_OLD 4096
#define FK 512
#define LCAP 3072
#define SCAP 24                      /* per-(block,class) staging cap */
#define CSTR 16                      /* cnts stride in u32 (64B line pad) */
#define CUT 0.5f
#define BINW 0.001953125f            /* (1-CUT)/256 exact */
#define HS2 512.0f                   /* 256/(1-CUT) */
#define RSC 262144.0f                /* 512/BINW */
#define BPI 394                      /* blocks per image: 19 + 75 + 300 */
#define FBBINS 2048                  /* fallback hist bins (8 KB overlay) */

__constant__ float c_AW[9] = {10.f,16.f,33.f,30.f,62.f,59.f,116.f,156.f,373.f};
__constant__ float c_AH[9] = {13.f,30.f,23.f,61.f,45.f,119.f,90.f,198.f,326.f};

__device__ __forceinline__ float sigmoidf_(float x) { return 1.0f / (1.0f + expf(-x)); }

__device__ __forceinline__ void box_loc(int i, const float* p5, const float* p4, const float* p3,
                                        const float*& p, int& g, int& li, int& abase) {
  if (i < 1200)      { p = p5; g = 20; li = i;        abase = 6; }
  else if (i < 6000) { p = p4; g = 40; li = i - 1200; abase = 3; }
  else               { p = p3; g = 80; li = i - 6000; abase = 0; }
}

// exact ref-rounding score recomputed from raw logits (fallback paths only)
__device__ __forceinline__ float score_full(const float* p5, const float* p4, const float* p3,
                                            int b, int c, int i) {
  const float* p; int g, li, abase;
  box_loc(i, p5, p4, p3, p, g, li, abase);
  const float* f = p + (size_t)((size_t)b * g * g * 3 + li) * 85;
  return __fmul_rn(sigmoidf_(f[4]), sigmoidf_(f[5 + c]));
}

// exact ref-rounding box recomputed from raw logits (identical ops to reference)
__device__ __forceinline__ float4 decode_box(const float* p5, const float* p4, const float* p3,
                                             int b, int i) {
  const float* p; int g, li, abase;
  box_loc(i, p5, p4, p3, p, g, li, abase);
  const float* f = p + (size_t)((size_t)b * g * g * 3 + li) * 85;
  int cell = li / 3, a = li - cell * 3;
  float ratio = 640.0f / (float)g;
  float cx = (sigmoidf_(f[0]) + (float)(cell % g)) * ratio;
  float cy = (sigmoidf_(f[1]) + (float)(cell / g)) * ratio;
  float w = expf(f[2]) * c_AW[abase + a];
  float h = expf(f[3]) * c_AH[abase + a];
  float hw = 0.5f * w, hh = 0.5f * h;
  return make_float4(cx - hw, cy - hh, cx + hw, cy + hh);
}

// ============ Kernel A: candidate scan only (boxes recomputed downstream) ============
__global__ __launch_bounds__(512) void decode_push_kernel(
    const float* __restrict__ p5, const float* __restrict__ p4, const float* __restrict__ p3,
    unsigned long long* __restrict__ lists, uint32_t* __restrict__ cnts,
    uint32_t* __restrict__ ovfl)
{
  __shared__ float rec[64 * 85];                   // 21.76 KB: 64 contiguous records
  __shared__ unsigned long long slist[NCLS][SCAP]; // 15.36 KB staging
  __shared__ uint32_t wcnt[NCLS];
  __shared__ uint32_t sbase[NCLS], sst[NCLS];
  __shared__ unsigned short pairbuf[8 * 64];       // 1 KB: per-wave survivor pairs

  const int bi = blockIdx.x;
  const int b = bi / BPI, r = bi - b * BPI;
  const float* p; int g, lb, s0, nb;
  if (r < 19)      { p = p5; g = 20; lb = 0;    s0 = r * 64;        nb = 1200  - s0; }
  else if (r < 94) { p = p4; g = 40; lb = 1200; s0 = (r - 19) * 64; nb = 4800  - s0; }
  else             { p = p3; g = 80; lb = 6000; s0 = (r - 94) * 64; nb = 19200 - s0; }
  if (nb > 64) nb = 64;
  const int tid = threadIdx.x;

  if (tid < NCLS) wcnt[tid] = 0;
  {
    const float4* src4 = (const float4*)(p + ((size_t)b * g * g * 3 + s0) * 85);
    float4* rec4 = (float4*)rec;
    int n4 = nb * 85 / 4;
    for (int k = tid; k < n4; k += 512) rec4[k] = src4[k];
  }
  __syncthreads();

  // class scan: wave w owns classes [10w, 10w+10); logit-threshold prune,
  // wave-compacted survivors, dense exact-sigmoid flush (candidate set exact).
  {
    const int wave = tid >> 6, lane = tid & 63;
    const int c0 = wave * 10;
    const bool jok = lane < nb;
    float cl = jok ? rec[lane * 85 + 4] : -1.0f;   // conf logit
    float Lthr;
    if (!jok || cl <= 0.0f) {
      Lthr = 3.0e38f;                              // conf <= 0.5 -> s < 0.5 always
    } else {
      float conf = 1.0f / (1.0f + expf(-cl));
      float u2 = CUT / conf;                       // (0.5, 1)
      if (u2 > 0.999f) Lthr = -3.0e38f;            // near-boundary conf: exact all classes
      else Lthr = logf(u2 / (1.0f - u2)) - 0.01f;  // margin >> fp error of L
    }
    const float* fl = rec + lane * 85 + 5;
    const unsigned long long lt = (lane == 0) ? 0ull : (~0ull >> (64 - lane));
    unsigned short* pb = pairbuf + (wave << 6);

    auto flushFn = [&](int mm) {
      if (lane < mm) {
        int e = pb[lane];
        int l2 = e >> 4, cc2 = e & 15;
        int c2 = c0 + cc2;
        float s = __fmul_rn(sigmoidf_(rec[l2 * 85 + 4]), sigmoidf_(rec[l2 * 85 + 5 + c2]));
        if (s > CUT) {
          uint32_t slot = atomicAdd(&wcnt[c2], 1u);
          if (slot < SCAP)
            slist[c2][slot] = ((unsigned long long)__float_as_uint(s) << 32)
                              | (0xFFFFFFFFu - (uint32_t)(lb + s0 + l2));
        }
      }
    };

    int m = 0;
    for (int cc = 0; cc < 10; ++cc) {
      float lg = jok ? fl[c0 + cc] : -3.0e38f;
      bool cand = lg > Lthr;
      unsigned long long mk = __ballot(cand);
      int pc = __popcll(mk);
      if (m + pc > 64) { flushFn(m); m = 0; }
      if (cand) {
        int rank = __popcll(mk & lt);
        pb[m + rank] = (unsigned short)((lane << 4) | cc);
      }
      m += pc;
    }
    flushFn(m);
  }
  __syncthreads();

  if (tid < NCLS) {
    uint32_t full = wcnt[tid];
    if (full > SCAP) ovfl[b * NCLS + tid] = 1u;
    uint32_t st = full < SCAP ? full : SCAP;
    sst[tid] = st;
    sbase[tid] = atomicAdd(&cnts[(size_t)(b * NCLS + tid) * CSTR], st);
  }
  __syncthreads();

  for (int t = tid; t < NCLS * SCAP; t += 512) {
    int c = t / SCAP, k = t - c * SCAP;
    if ((uint32_t)k < sst[c]) {
      uint32_t dst = sbase[c] + (uint32_t)k;
      if (dst < LCAP)
        lists[(size_t)(b * NCLS + c) * LCAP + dst] = slist[c][k];
    }
  }
}

// ============ Kernel B: select + hybrid sort + wave-scan bitmask NMS (512 thr) ============
union ShMix2 {
  uint32_t rhist[512];                  // refine hist (2 KB)
  uint32_t fhist[FBBINS];               // fallback hist (8 KB)
  unsigned long long rowm[KPRE][4];     // IoU adjacency rows (8 KB)
};

__global__ __launch_bounds__(512) void select_nms_list_kernel(
    const unsigned long long* __restrict__ lists, const uint32_t* __restrict__ cnts,
    const uint32_t* __restrict__ ovfl,
    const float* __restrict__ p5, const float* __restrict__ p4, const float* __restrict__ p3,
    float* __restrict__ kept_s, int* __restrict__ top_i)
{
  const int task = blockIdx.x;
  const int b = task / NCLS, c = task - b * NCLS;
  const int tid = threadIdx.x;

  __shared__ uint32_t S[256];
  __shared__ unsigned long long keys[GCAP];      // 4 KB
  __shared__ ShMix2 u;                           // 8 KB
  __shared__ float4 bbx[KPRE];                   // 4 KB
  __shared__ float bar_[KPRE];                   // 1 KB
  __shared__ unsigned long long suppInit[4];
  __shared__ unsigned long long sh_t[4];
  __shared__ int s_B, s_cnt, s_state, sh_stop;
  __shared__ float s_gl, s_lo, s_hi;
  __shared__ uint32_t s_above, s_g2;

  const uint32_t cntraw = cnts[(size_t)task * CSTR];
  bool fb = (ovfl[task] != 0u) || !(cntraw >= (uint32_t)KPRE && cntraw <= (uint32_t)LCAP);
  float thr = CUT;
  int n_all = (int)(cntraw < (uint32_t)LCAP ? cntraw : (uint32_t)LCAP);
  const unsigned long long* gl = lists + (size_t)task * LCAP;

  if (!fb && n_all > 500) {
    if (tid < 256) S[tid] = 0;
    __syncthreads();
    for (int z = tid; z < n_all; z += 512) {
      float s = __uint_as_float((uint32_t)(gl[z] >> 32));
      int bin = (int)(__fmul_rn(__fsub_rn(s, CUT), HS2));
      bin = bin < 0 ? 0 : (bin > 255 ? 255 : bin);
      atomicAdd(&S[bin], 1u);
    }
    __syncthreads();
    for (int off = 1; off < 256; off <<= 1) {     // suffix scan: S[z] = count(bin >= z)
      uint32_t add = 0;
      if (tid < 256 && tid + off < 256) add = S[tid + off];
      __syncthreads();
      if (tid < 256) S[tid] += add;
      __syncthreads();
    }
    if (tid == 0) s_B = 0;
    __syncthreads();
    if (tid < 256) {
      uint32_t Sz = S[tid];
      uint32_t Sz1 = (tid < 255) ? S[tid + 1] : 0u;
      if (Sz >= KPRE && (tid == 255 || Sz1 < KPRE)) s_B = tid;
    }
    __syncthreads();
    const int B = s_B;
    const uint32_t gcount = S[B];
    const uint32_t aboveB = (B < 255) ? S[B + 1] : 0u;
    thr = CUT + (float)B * BINW;
    if (gcount > 500u) {
      for (int z = tid; z < 512; z += 512) u.rhist[z] = 0u;
      __syncthreads();
      float rLo = thr;
      for (int z = tid; z < n_all; z += 512) {
        float s = __uint_as_float((uint32_t)(gl[z] >> 32));
        int bin = (int)(__fmul_rn(__fsub_rn(s, CUT), HS2));
        bin = bin < 0 ? 0 : (bin > 255 ? 255 : bin);
        if (bin == B) {
          int sub = (int)((s - rLo) * RSC);
          sub = sub < 0 ? 0 : (sub > 511 ? 511 : sub);
          atomicAdd(&u.rhist[sub], 1u);
        }
      }
      __syncthreads();
      if (tid == 0) {
        uint32_t acc = aboveB; int B2 = 0;
        for (int z = 511; z >= 0; --z) {
          acc += u.rhist[z];
          if (acc >= KPRE) { B2 = z; break; }
        }
        s_gl = rLo + (float)B2 * (BINW / 512.0f);
        s_g2 = acc;
      }
      __syncthreads();
      thr = s_gl;
      if (s_g2 > 500u) fb = true;
      __syncthreads();
    }
  }

  if (fb) {
    // exact fallback: iterative strided hist over raw scores (never taken on bench data)
    float lo = SCORE_THR, hi = 1.0f;
    uint32_t above = 0;
    float gl2 = SCORE_THR;
    bool done = false;
    for (int iter = 0; iter < 6 && !done; ++iter) {
      for (int z = tid; z < FBBINS; z += 512) u.fhist[z] = 0u;
      __syncthreads();
      float scale = (float)FBBINS / (hi - lo);
      for (int i = tid; i < NBOX; i += 512) {
        float s = score_full(p5, p4, p3, b, c, i);
        if (s > lo && s <= hi) {
          int bin = (int)((s - lo) * scale);
          bin = bin < 0 ? 0 : (bin > FBBINS - 1 ? FBBINS - 1 : bin);
          atomicAdd(&u.fhist[bin], 1u);
        }
      }
      __syncthreads();
      if (tid < 256) {
        uint32_t cs = 0; int base = tid * 8;
        #pragma unroll
        for (int z = 0; z < 8; ++z) cs += u.fhist[base + z];
        S[tid] = cs;
      }
      __syncthreads();
      if (tid == 0) {
        uint32_t acc = 0; int ch;
        for (ch = 255; ch >= 0; --ch) {
          if (above + acc + S[ch] >= KPRE) break;
          acc += S[ch];
        }
        if (ch < 0) { s_state = 1; s_gl = SCORE_THR; }
        else {
          int B = -1;
          for (int z = ch * 8 + 7; z >= ch * 8; --z) {
            acc += u.fhist[z];
            if (above + acc >= KPRE) { B = z; break; }
          }
          uint32_t popB = u.fhist[B];
          uint32_t aboveNew = above + acc - popB;
          float wdt = (hi - lo) / (float)FBBINS;
          float binLo = lo + (float)B * wdt;
          if (aboveNew + popB <= 496u || iter == 5) { s_state = 1; s_gl = binLo; }
          else { s_state = 0; s_lo = binLo; s_hi = binLo + wdt; s_above = aboveNew; }
        }
      }
      __syncthreads();
      if (s_state == 1) { gl2 = s_gl; done = true; }
      else { lo = s_lo; hi = s_hi; above = s_above; }
      __syncthreads();
    }
    thr = gl2;
  }

  float thr_n = __uint_as_float(__float_as_uint(thr) - 8u);   // ulp nudge vs bin rounding

  if (tid == 0) s_cnt = 0;
  __syncthreads();
  if (!fb) {
    for (int z = tid; z < n_all; z += 512) {
      unsigned long long kk = gl[z];
      float s = __uint_as_float((uint32_t)(kk >> 32));
      if (s > thr_n) {
        int slot = atomicAdd(&s_cnt, 1);
        if (slot < GCAP) keys[slot] = kk;
      }
    }
  } else {
    for (int i = tid; i < NBOX; i += 512) {
      float s = score_full(p5, p4, p3, b, c, i);
      if (s > thr_n && s > SCORE_THR) {
        int slot = atomicAdd(&s_cnt, 1);
        if (slot < GCAP)
          keys[slot] = ((unsigned long long)__float_as_uint(s) << 32) | (0xFFFFFFFFu - (uint32_t)i);
      }
    }
  }
  __syncthreads();
  int n = s_cnt < GCAP ? s_cnt : GCAP;
  if (tid >= n) keys[tid] = 0ull;
  __syncthreads();
  // hybrid bitonic sort 512 descending: j<64 via register shfl_xor, j>=64 via LDS
  {
    unsigned long long v = keys[tid];
    for (int k = 2; k <= GCAP; k <<= 1) {
      for (int j = k >> 1; j > 0; j >>= 1) {
        unsigned long long pv;
        if (j >= 64) {
          keys[tid] = v;
          __syncthreads();
          pv = keys[tid ^ j];
          __syncthreads();
        } else {
          pv = __shfl_xor(v, j, 64);
        }
        bool takeMax = (((tid & k) == 0) == ((tid & j) == 0));
        v = takeMax ? (v > pv ? v : pv) : (v < pv ? v : pv);
      }
    }
    keys[tid] = v;
  }
  __syncthreads();

  // ---- chunked bitmask NMS on top-256, wave-register suppression scan ----
  const int col = tid & 255;
  float sc; int idx;
  {
    unsigned long long kk = keys[col];
    if ((uint32_t)(kk >> 32) != 0u) { sc = __uint_as_float((uint32_t)(kk >> 32)); idx = (int)(0xFFFFFFFFu - (uint32_t)kk); }
    else { sc = -1.0f; idx = 0; }
  }
  if (tid < KPRE) {
    float4 bx = decode_box(p5, p4, p3, b, idx);
    bbx[tid] = bx;
    bar_[tid] = __fmul_rn(fmaxf(__fsub_rn(bx.z, bx.x), 0.0f), fmaxf(__fsub_rn(bx.w, bx.y), 0.0f));
  }
  {
    unsigned long long alive = __ballot(sc > SCORE_THR);
    if (tid < KPRE && (tid & 63) == 0) suppInit[tid >> 6] = ~alive;
  }
  if (tid == 0) sh_stop = 0;
  __syncthreads();
  float4 MB = bbx[col];
  float x1 = MB.x, y1 = MB.y, x2 = MB.z, y2 = MB.w;
  float area = bar_[col];
  if (tid < 4) sh_t[tid] = suppInit[tid];
  __syncthreads();

  int P = 4;
  const int rg = tid >> 8;                       // row-group: 0 or 1
  #pragma unroll
  for (int q = 0; q < 4; ++q) {
    for (int ii = 0; ii < 64; ii += 2) {
      int i = q * 64 + ii + rg;
      if (!((sh_t[q] >> (ii + rg)) & 1ull)) {
        float4 B = bbx[i];
        float ar = bar_[i];
        float iw = fmaxf(__fsub_rn(fminf(x2, B.z), fmaxf(x1, B.x)), 0.0f);
        float ih = fmaxf(__fsub_rn(fminf(y2, B.w), fmaxf(y1, B.y)), 0.0f);
        float inter = __fmul_rn(iw, ih);
        float ab = __fadd_rn(ar, area);
        float diff = __fsub_rn(__fmul_rn(inter, 1.1f), __fmul_rn(0.1f, ab));
        bool sup;
        if (fabsf(diff) > 1e-5f * ab) {
          sup = diff > 0.0f;
        } else {
          float uni = __fsub_rn(ab, inter);
          sup = (inter / fmaxf(uni, 1e-9f)) > IOU_THR;
        }
        sup = sup && (col > i);
        unsigned long long m = __ballot(sup);
        if ((tid & 63) == 0) u.rowm[i][(tid >> 6) & 3] = m;
      }
    }
    __syncthreads();
    if (tid < 64) {                              // wave-register serial scan (uniform branches)
      unsigned long long r0 = u.rowm[q * 64 + tid][0];
      unsigned long long r1 = u.rowm[q * 64 + tid][1];
      unsigned long long r2 = u.rowm[q * 64 + tid][2];
      unsigned long long r3 = u.rowm[q * 64 + tid][3];
      unsigned long long t0 = sh_t[0], t1 = sh_t[1], t2 = sh_t[2], t3 = sh_t[3];
      unsigned long long tq = (q == 0) ? t0 : (q == 1) ? t1 : (q == 2) ? t2 : t3;
      for (int ii = 0; ii < 64; ++ii) {
        if (!((tq >> ii) & 1ull)) {
          t0 |= __shfl(r0, ii); t1 |= __shfl(r1, ii);
          t2 |= __shfl(r2, ii); t3 |= __shfl(r3, ii);
          tq = (q == 0) ? t0 : (q == 1) ? t1 : (q == 2) ? t2 : t3;
        }
      }
      if (tid == 0) {
        sh_t[0] = t0; sh_t[1] = t1; sh_t[2] = t2; sh_t[3] = t3;
        int kept = __popcll(~t0);
        if (q >= 1) kept += __popcll(~t1);
        if (q >= 2) kept += __popcll(~t2);
        if (q >= 3) kept += __popcll(~t3);
        if (kept >= MAXB) sh_stop = 1;           // rows beyond can't enter the top-100
      }
    }
    __syncthreads();
    if (sh_stop) { P = q + 1; break; }
  }

  if (tid < KPRE) {
    unsigned long long tw = sh_t[tid >> 6];
    bool kept = (tid < 64 * P) && !((tw >> (tid & 63)) & 1ull);
    int rank = 0;
    #pragma unroll
    for (int w2 = 0; w2 < 4; ++w2)
      if (w2 < (tid >> 6)) rank += __popcll(~sh_t[w2]);
    int l = tid & 63;
    rank += (l == 0) ? 0 : __popcll(~tw & ((~0ull) >> (64 - l)));
    bool fin = kept && (rank < MAXB);
    kept_s[(size_t)task * KPRE + tid] = fin ? sc : -1.0f;
    top_i[(size_t)task * KPRE + tid] = idx;
  }
}

// ============ Small-ws fallback path (round-0/1, validated, 256 thr) ============
__global__ __launch_bounds__(256) void decode_kernel(
    const float* __restrict__ p5, const float* __restrict__ p4, const float* __restrict__ p3,
    float* __restrict__ boxes, float* __restrict__ conf)
{
  int t = blockIdx.x * 256 + threadIdx.x;
  if (t >= NIMG * NBOX) return;
  int b = t / NBOX, i = t - b * NBOX;
  float4 bx = decode_box(p5, p4, p3, b, i);
  float* ob = boxes + (size_t)t * 4;
  ob[0] = bx.x; ob[1] = bx.y; ob[2] = bx.z; ob[3] = bx.w;
  const float* p; int g, li, abase;
  box_loc(i, p5, p4, p3, p, g, li, abase);
  conf[t] = sigmoidf_(p[(size_t)((size_t)b * g * g * 3 + li) * 85 + 4]);
}

__device__ __forceinline__ float score_at(
    const float* __restrict__ p5, const float* __restrict__ p4, const float* __restrict__ p3,
    const float* __restrict__ conf, int b, int c, int i)
{
  const float* p; int g, li, abase;
  box_loc(i, p5, p4, p3, p, g, li, abase);
  float logit = p[(size_t)((size_t)b * g * g * 3 + li) * 85 + 5 + c];
  return __fmul_rn(conf[b * NBOX + i], 1.0f / (1.0f + expf(-logit)));
}

__global__ __launch_bounds__(256) void select_nms_kernel(
    const float* __restrict__ p5, const float* __restrict__ p4, const float* __restrict__ p3,
    const float* __restrict__ conf, const float* __restrict__ boxes,
    float* __restrict__ kept_s, int* __restrict__ top_i)
{
  const int task = blockIdx.x;
  const int b = task / NCLS, c = task - b * NCLS;
  const int tid = threadIdx.x;
  __shared__ uint32_t hist[NBINS_OLD];
  __shared__ uint32_t chunkS[256];
  __shared__ unsigned long long keys[GCAP_OLD];
  __shared__ float s_lo, s_hi, s_glo;
  __shared__ uint32_t s_above;
  __shared__ int s_state, s_cnt;

  float lo = SCORE_THR, hi = 1.0f;
  uint32_t above = 0;
  float gatherLo = SCORE_THR;
  bool done = false;
  for (int iter = 0; iter < 6 && !done; ++iter) {
    for (int z = tid; z < NBINS_OLD; z += 256) hist[z] = 0;
    __syncthreads();
    float scale = (float)NBINS_OLD / (hi - lo);
    for (int i = tid; i < NBOX; i += 256) {
      float s = score_at(p5, p4, p3, conf, b, c, i);
      if (s > lo && s <= hi) {
        int bin = (int)((s - lo) * scale);
        bin = bin < 0 ? 0 : (bin > NBINS_OLD - 1 ? NBINS_OLD - 1 : bin);
        atomicAdd(&hist[bin], 1u);
      }
    }
    __syncthreads();
    { uint32_t cs = 0; int base = tid * 16;
      #pragma unroll
      for (int z = 0; z < 16; ++z) cs += hist[base + z];
      chunkS[tid] = cs; }
    __syncthreads();
    if (tid == 0) {
      uint32_t acc = 0; int ch;
      for (ch = 255; ch >= 0; --ch) {
        if (above + acc + chunkS[ch] >= KPRE) break;
        acc += chunkS[ch];
      }
      if (ch < 0) { s_state = 1; s_glo = SCORE_THR; }
      else {
        int B = -1;
        for (int z = ch * 16 + 15; z >= ch * 16; --z) {
          acc += hist[z];
          if (above + acc >= KPRE) { B = z; break; }
        }
        uint32_t popB = hist[B];
        uint32_t aboveNew = above + acc - popB;
        float wdt = (hi - lo) / (float)NBINS_OLD;
        float binLo = lo + (float)B * wdt;
        if (aboveNew + popB <= 1024u || iter == 5) { s_state = 1; s_glo = binLo; }
        else { s_state = 0; s_lo = binLo; s_hi = binLo + wdt; s_above = aboveNew; }
      }
    }
    __syncthreads();
    if (s_state == 1) { gatherLo = s_glo; done = true; }
    else { lo = s_lo; hi = s_hi; above = s_above; }
    __syncthreads();
  }
  gatherLo = __uint_as_float(__float_as_uint(gatherLo) - 8u);
  if (tid == 0) s_cnt = 0;
  __syncthreads();
  for (int i = tid; i < NBOX; i += 256) {
    float s = score_at(p5, p4, p3, conf, b, c, i);
    if (s > gatherLo && s > SCORE_THR) {
      int slot = atomicAdd(&s_cnt, 1);
      if (slot < GCAP_OLD)
        keys[slot] = ((unsigned long long)__float_as_uint(s) << 32) | (uint32_t)(0xFFFFFFFFu - (uint32_t)i);
    }
  }
  __syncthreads();
  int n = s_cnt < GCAP_OLD ? s_cnt : GCAP_OLD;
  for (int z = tid; z < GCAP_OLD; z += 256) if (z >= n) keys[z] = 0ull;
  __syncthreads();
  for (int k = 2; k <= GCAP_OLD; k <<= 1) {
    for (int j = k >> 1; j > 0; j >>= 1) {
      for (int i2 = tid; i2 < GCAP_OLD; i2 += 256) {
        int ixj = i2 ^ j;
        if (ixj > i2) {
          unsigned long long a0 = keys[i2], b0_ = keys[ixj];
          bool sw = ((i2 & k) == 0) ? (a0 < b0_) : (a0 > b0_);
          if (sw) { keys[i2] = b0_; keys[ixj] = a0; }
        }
      }
      __syncthreads();
    }
  }
  __shared__ float bx1[KPRE], by1[KPRE], bx2[KPRE], by2[KPRE], bar_[KPRE], tsc[KPRE];
  __shared__ int tix[KPRE];
  __shared__ unsigned char suppA[KPRE], keepA[KPRE];
  { int r = tid;
    unsigned long long kk = keys[r];
    float sc; int idx;
    if ((uint32_t)(kk >> 32) != 0u) { sc = __uint_as_float((uint32_t)(kk >> 32)); idx = (int)(0xFFFFFFFFu - (uint32_t)kk); }
    else { sc = -1.0f; idx = 0; }
    tsc[r] = sc; tix[r] = idx;
    const float* bp = boxes + ((size_t)b * NBOX + idx) * 4;
    float x1 = bp[0], y1 = bp[1], x2 = bp[2], y2 = bp[3];
    bx1[r] = x1; by1[r] = y1; bx2[r] = x2; by2[r] = y2;
    bar_[r] = __fmul_rn(fmaxf(__fsub_rn(x2, x1), 0.0f), fmaxf(__fsub_rn(y2, y1), 0.0f));
    suppA[r] = (sc <= SCORE_THR) ? 1 : 0; }
  __syncthreads();
  for (int i = 0; i < KPRE; ++i) {
    if (suppA[i] == 0) {
      int r = tid;
      if (r > i) {
        float iw = fmaxf(__fsub_rn(fminf(bx2[r], bx2[i]), fmaxf(bx1[r], bx1[i])), 0.0f);
        float ih = fmaxf(__fsub_rn(fminf(by2[r], by2[i]), fmaxf(by1[r], by1[i])), 0.0f);
        float inter = __fmul_rn(iw, ih);
        float uni = __fsub_rn(__fadd_rn(bar_[r], bar_[i]), inter);
        float iou = inter / fmaxf(uni, 1e-9f);
        if (iou > IOU_THR) suppA[r] = 1;
      }
    }
    __syncthreads();
  }
  if (tid == 0) {
    int cnt = 0;
    for (int r = 0; r < KPRE; ++r) {
      int kp = (suppA[r] == 0) ? 1 : 0;
      if (kp && cnt < MAXB) cnt++; else kp = 0;
      keepA[r] = (unsigned char)kp;
    }
  }
  __syncthreads();
  { int r = tid;
    kept_s[(size_t)task * KPRE + r] = keepA[r] ? tsc[r] : -1.0f;
    top_i[(size_t)task * KPRE + r] = tix[r]; }
}

// ============ Kernel C: per-image final top-100 (boxes recomputed from logits) ============
__global__ __launch_bounds__(256) void final_topk_kernel(
    const float* __restrict__ kept_s, const int* __restrict__ top_i,
    const float* __restrict__ p5, const float* __restrict__ p4, const float* __restrict__ p3,
    float* __restrict__ out)
{
  int b = blockIdx.x, tid = threadIdx.x;
  __shared__ uint32_t hist[NBINS_OLD];
  __shared__ uint32_t chunkS[256];
  __shared__ unsigned long long keys[FK];
  __shared__ float s_lo, s_hi, s_glo;
  __shared__ uint32_t s_above;
  __shared__ int s_state, s_cnt;
  const float* ks = kept_s + (size_t)b * NCLS * KPRE;
  const int NK = NCLS * KPRE;

  float lo = SCORE_THR, hi = 1.0f;
  uint32_t above = 0;
  float gatherLo = SCORE_THR;
  bool done = false;

  for (int iter = 0; iter < 4 && !done; ++iter) {
    for (int z = tid; z < NBINS_OLD; z += 256) hist[z] = 0;
    __syncthreads();
    float scale = (float)NBINS_OLD / (hi - lo);
    for (int z = tid; z < NK; z += 256) {
      float s = ks[z];
      if (s > lo && s <= hi) {
        int bin = (int)((s - lo) * scale);
        bin = bin < 0 ? 0 : (bin > NBINS_OLD - 1 ? NBINS_OLD - 1 : bin);
        atomicAdd(&hist[bin], 1u);
      }
    }
    __syncthreads();
    {
      uint32_t cs = 0; int base = tid * 16;
      #pragma unroll
      for (int z = 0; z < 16; ++z) cs += hist[base + z];
      chunkS[tid] = cs;
    }
    __syncthreads();
    if (tid == 0) {
      uint32_t acc = 0; int ch;
      for (ch = 255; ch >= 0; --ch) {
        if (above + acc + chunkS[ch] >= MAXB) break;
        acc += chunkS[ch];
      }
      if (ch < 0) { s_state = 1; s_glo = SCORE_THR; }
      else {
        int B = -1;
        for (int z = ch * 16 + 15; z >= ch * 16; --z) {
          acc += hist[z];
          if (above + acc >= MAXB) { B = z; break; }
        }
        uint32_t popB = hist[B];
        uint32_t aboveNew = above + acc - popB;
        float wdt = (hi - lo) / (float)NBINS_OLD;
        float binLo = lo + (float)B * wdt;
        if (aboveNew + popB <= (uint32_t)(FK - 64) || iter == 3) { s_state = 1; s_glo = binLo; }
        else { s_state = 0; s_lo = binLo; s_hi = binLo + wdt; s_above = aboveNew; }
      }
    }
    __syncthreads();
    if (s_state == 1) { gatherLo = s_glo; done = true; }
    else { lo = s_lo; hi = s_hi; above = s_above; }
    __syncthreads();
  }
  gatherLo = __uint_as_float(__float_as_uint(gatherLo) - 8u);

  if (tid == 0) s_cnt = 0;
  __syncthreads();
  for (int z = tid; z < NK; z += 256) {
    float s = ks[z];
    if (s > gatherLo && s > 0.0f) {
      int slot = atomicAdd(&s_cnt, 1);
      if (slot < FK)
        keys[slot] = ((unsigned long long)__float_as_uint(s) << 32) | (uint32_t)(0xFFFFFFFFu - (uint32_t)z);
    }
  }
  __syncthreads();
  int n = s_cnt < FK ? s_cnt : FK;
  for (int z = tid; z < FK; z += 256) if (z >= n) keys[z] = 0ull;
  __syncthreads();
  for (int k = 2; k <= FK; k <<= 1) {
    for (int j = k >> 1; j > 0; j >>= 1) {
      for (int i2 = tid; i2 < FK; i2 += 256) {
        int ixj = i2 ^ j;
        if (ixj > i2) {
          unsigned long long a0 = keys[i2], b0_ = keys[ixj];
          bool sw = ((i2 & k) == 0) ? (a0 < b0_) : (a0 > b0_);
          if (sw) { keys[i2] = b0_; keys[ixj] = a0; }
        }
      }
      __syncthreads();
    }
  }
  float* ob = out + (size_t)b * MAXB * 4;
  float* os = out + (size_t)NIMG * MAXB * 4 + (size_t)b * MAXB;
  float* ol = out + (size_t)NIMG * MAXB * 4 + (size_t)NIMG * MAXB + (size_t)b * MAXB;
  for (int t = tid; t < MAXB; t += 256) {
    unsigned long long kk = keys[t];
    if ((uint32_t)(kk >> 32) != 0u) {
      float s = __uint_as_float((uint32_t)(kk >> 32));
      int fr = (int)(0xFFFFFFFFu - (uint32_t)kk);     // c*256 + r (class-major flat order)
      int cc = fr >> 8, rr = fr & 255;
      int idx = top_i[((size_t)b * NCLS + cc) * KPRE + rr];
      float4 bx = decode_box(p5, p4, p3, b, idx);
      ob[t * 4 + 0] = bx.x; ob[t * 4 + 1] = bx.y; ob[t * 4 + 2] = bx.z; ob[t * 4 + 3] = bx.w;
      os[t] = s; ol[t] = (float)cc;
    } else {
      ob[t * 4 + 0] = -1.0f; ob[t * 4 + 1] = -1.0f; ob[t * 4 + 2] = -1.0f; ob[t * 4 + 3] = -1.0f;
      os[t] = -1.0f; ol[t] = -1.0f;
    }
  }
}

extern "C" void kernel_launch(void* const* d_in, const int* in_sizes, int n_in,
                              void* d_out, int out_size, void* d_ws, size_t ws_size,
                              hipStream_t stream)
{
  const float* p5 = (const float*)d_in[0];
  const float* p4 = (const float*)d_in[1];
  const float* p3 = (const float*)d_in[2];
  float* out = (float*)d_out;

  float*    boxes  = (float*)d_ws;                                   // fallback only
  float*    kept   = boxes + (size_t)NIMG * NBOX * 4;                // 1280*256 f
  int*      topi   = (int*)(kept + (size_t)NIMG * NCLS * KPRE);      // 1280*256 i
  uint32_t* cnts   = (uint32_t*)(topi + (size_t)NIMG * NCLS * KPRE); // 1280*16 u32
  uint32_t* ovfl   = cnts + (size_t)NIMG * NCLS * CSTR;              // 1280 u32
  unsigned long long* lists = (unsigned long long*)(ovfl + NIMG * NCLS); // 1280*3072 u64

  size_t need_main = ((size_t)NIMG * NBOX * 4 + (size_t)NIMG * NCLS * KPRE * 2
                      + (size_t)NIMG * NCLS * CSTR + (size_t)NIMG * NCLS) * 4
                     + (size_t)NIMG * NCLS * LCAP * 8;

  if (ws_size >= need_main) {
    hipMemsetAsync(cnts, 0,
                   ((size_t)NIMG * NCLS * CSTR + (size_t)NIMG * NCLS) * sizeof(uint32_t),
                   stream);
    decode_push_kernel<<<NIMG * BPI, 512, 0, stream>>>(p5, p4, p3, lists, cnts, ovfl);
    select_nms_list_kernel<<<NIMG * NCLS, 512, 0, stream>>>(lists, cnts, ovfl, p5, p4, p3,
                                                            kept, topi);
  } else {
    float* conf = (float*)lists;                                     // overlay (fallback only)
    decode_kernel<<<(NIMG * NBOX + 255) / 256, 256, 0, stream>>>(p5, p4, p3, boxes, conf);
    select_nms_kernel<<<NIMG * NCLS, 256, 0, stream>>>(p5, p4, p3, conf, boxes, kept, topi);
  }
  final_topk_kernel<<<NIMG, 256, 0, stream>>>(kept, topi, p5, p4, p3, out);
}

// Round 12
// 206.700 us; speedup vs baseline: 1.6225x; 1.0483x over previous
//
#include <hip/hip_runtime.h>
#include <cstdint>

#define NBOX 25200
#define NCLS 80
#define NIMG 16
#define KPRE 256
#define MAXB 100
#define SCORE_THR 0.25f
#define IOU_THR 0.1f
#define GCAP 512
#define GCAP_OLD 2048
#define NBINS_OLD 4096
#define FK 512
#define LCAP 3072
#define SCAP 24                      /* per-(block,class) staging cap */
#define CSTR 16                      /* cnts stride in u32 (64B line pad) */
#define CUT 0.5f
#define BINW 0.001953125f            /* (1-CUT)/256 exact */
#define HS2 512.0f                   /* 256/(1-CUT) */
#define RSC 262144.0f                /* 512/BINW */
#define BPI 394                      /* blocks per image: 19 + 75 + 300 */
#define FBBINS 2048                  /* fallback hist bins (8 KB overlay) */

__constant__ float c_AW[9] = {10.f,16.f,33.f,30.f,62.f,59.f,116.f,156.f,373.f};
__constant__ float c_AH[9] = {13.f,30.f,23.f,61.f,45.f,119.f,90.f,198.f,326.f};

__device__ __forceinline__ float sigmoidf_(float x) { return 1.0f / (1.0f + expf(-x)); }

__device__ __forceinline__ void box_loc(int i, const float* p5, const float* p4, const float* p3,
                                        const float*& p, int& g, int& li, int& abase) {
  if (i < 1200)      { p = p5; g = 20; li = i;        abase = 6; }
  else if (i < 6000) { p = p4; g = 40; li = i - 1200; abase = 3; }
  else               { p = p3; g = 80; li = i - 6000; abase = 0; }
}

// exact ref-rounding score recomputed from raw logits (fallback paths only)
__device__ __forceinline__ float score_full(const float* p5, const float* p4, const float* p3,
                                            int b, int c, int i) {
  const float* p; int g, li, abase;
  box_loc(i, p5, p4, p3, p, g, li, abase);
  const float* f = p + (size_t)((size_t)b * g * g * 3 + li) * 85;
  return __fmul_rn(sigmoidf_(f[4]), sigmoidf_(f[5 + c]));
}

// ============ Kernel A: decode + logit-threshold pruned, wave-compacted candidate push ============
__global__ __launch_bounds__(512) void decode_push_kernel(
    const float* __restrict__ p5, const float* __restrict__ p4, const float* __restrict__ p3,
    float* __restrict__ boxes, unsigned long long* __restrict__ lists,
    uint32_t* __restrict__ cnts, uint32_t* __restrict__ ovfl)
{
  __shared__ float rec[64 * 85];                   // 21.76 KB: 64 contiguous records
  __shared__ float conf_s[64];
  __shared__ unsigned long long slist[NCLS][SCAP]; // 15.36 KB staging
  __shared__ uint32_t wcnt[NCLS];                  // exact per-class pass count
  __shared__ uint32_t sbase[NCLS], sst[NCLS];
  __shared__ unsigned short pairbuf[8 * 64];       // 1 KB: per-wave survivor pairs

  const int bi = blockIdx.x;
  const int b = bi / BPI, r = bi - b * BPI;
  const float* p; int g, lb, s0, nb, abase;
  if (r < 19)      { p = p5; g = 20; lb = 0;    s0 = r * 64;        abase = 6; nb = 1200  - s0; }
  else if (r < 94) { p = p4; g = 40; lb = 1200; s0 = (r - 19) * 64; abase = 3; nb = 4800  - s0; }
  else             { p = p3; g = 80; lb = 6000; s0 = (r - 94) * 64; abase = 0; nb = 19200 - s0; }
  if (nb > 64) nb = 64;
  const int tid = threadIdx.x;

  if (tid < NCLS) wcnt[tid] = 0;
  {
    // coalesced stage via async global->LDS (16B/lane, wave-uniform base + lane*16);
    // tail float4s (n4 % 64) staged with the plain copy
    const float4* src4 = (const float4*)(p + ((size_t)b * g * g * 3 + s0) * 85);
    float4* rec4 = (float4*)rec;
    int n4 = nb * 85 / 4;                          // 1360 (nb=64) or 1020 (nb=48)
    int full = n4 >> 6;                            // full 64-float4 chunks
    const int wave = tid >> 6, lane = tid & 63;
    for (int ch = wave; ch < full; ch += 8) {
      int base = ch << 6;
      __builtin_amdgcn_global_load_lds(
          (const __attribute__((address_space(1))) void*)(uintptr_t)(src4 + base + lane),
          (__attribute__((address_space(3))) void*)(uintptr_t)(rec4 + base + lane),
          16, 0, 0);
    }
    for (int k = (full << 6) + tid; k < n4; k += 512) rec4[k] = src4[k];
  }
  __syncthreads();   // compiler drains vmcnt(0) before the barrier -> LDS data ready

  if (tid < nb) {
    const float* f = rec + tid * 85;
    int li = s0 + tid;
    int cell = li / 3, a = li - cell * 3;
    float ratio = 640.0f / (float)g;
    float cx = (sigmoidf_(f[0]) + (float)(cell % g)) * ratio;
    float cy = (sigmoidf_(f[1]) + (float)(cell / g)) * ratio;
    float w = expf(f[2]) * c_AW[abase + a];
    float h = expf(f[3]) * c_AH[abase + a];
    float hw = 0.5f * w, hh = 0.5f * h;
    float4* ob = (float4*)(boxes + ((size_t)b * NBOX + lb + li) * 4);
    *ob = make_float4(cx - hw, cy - hh, cx + hw, cy + hh);
    conf_s[tid] = sigmoidf_(f[4]);
  }
  __syncthreads();

  // phase A: wave w owns classes [10w, 10w+10)
  // logit-threshold prune (provably below CUT skipped), survivors wave-compacted,
  // dense exact-sigmoid flush. Exact candidate set identical to full evaluation.
  {
    const int wave = tid >> 6, lane = tid & 63;
    const int c0 = wave * 10;
    const bool jok = lane < nb;
    float cl = jok ? rec[lane * 85 + 4] : -1.0f;   // conf logit
    float Lthr;
    if (!jok || cl <= 0.0f) {
      Lthr = 3.0e38f;                              // conf <= 0.5 -> s < 0.5 always
    } else {
      float conf = conf_s[lane];
      float u2 = CUT / conf;                       // (0.5, 1)
      if (u2 > 0.999f) Lthr = -3.0e38f;            // near-boundary conf: exact all classes
      else Lthr = logf(u2 / (1.0f - u2)) - 0.01f;  // margin >> fp error of L
    }
    const float* fl = rec + lane * 85 + 5;
    const unsigned long long lt = (lane == 0) ? 0ull : (~0ull >> (64 - lane));
    unsigned short* pb = pairbuf + (wave << 6);

    auto flushFn = [&](int mm) {
      if (lane < mm) {
        int e = pb[lane];
        int l2 = e >> 4, cc2 = e & 15;
        int c2 = c0 + cc2;
        float s = __fmul_rn(conf_s[l2], sigmoidf_(rec[l2 * 85 + 5 + c2]));
        if (s > CUT) {
          uint32_t slot = atomicAdd(&wcnt[c2], 1u);
          if (slot < SCAP)
            slist[c2][slot] = ((unsigned long long)__float_as_uint(s) << 32)
                              | (0xFFFFFFFFu - (uint32_t)(lb + s0 + l2));
        }
      }
    };

    int m = 0;
    for (int cc = 0; cc < 10; ++cc) {
      float lg = jok ? fl[c0 + cc] : -3.0e38f;
      bool cand = lg > Lthr;
      unsigned long long mk = __ballot(cand);
      int pc = __popcll(mk);
      if (m + pc > 64) { flushFn(m); m = 0; }
      if (cand) {
        int rank = __popcll(mk & lt);
        pb[m + rank] = (unsigned short)((lane << 4) | cc);
      }
      m += pc;
    }
    flushFn(m);
  }
  __syncthreads();

  // phase B: overflow flag + one space reservation per class
  if (tid < NCLS) {
    uint32_t full = wcnt[tid];
    if (full > SCAP) ovfl[b * NCLS + tid] = 1u;
    uint32_t st = full < SCAP ? full : SCAP;
    sst[tid] = st;
    sbase[tid] = atomicAdd(&cnts[(size_t)(b * NCLS + tid) * CSTR], st);
  }
  __syncthreads();

  // phase C: bulk coalesced copy of staged keys
  for (int t = tid; t < NCLS * SCAP; t += 512) {
    int c = t / SCAP, k = t - c * SCAP;
    if ((uint32_t)k < sst[c]) {
      uint32_t dst = sbase[c] + (uint32_t)k;
      if (dst < LCAP)
        lists[(size_t)(b * NCLS + c) * LCAP + dst] = slist[c][k];
    }
  }
}

// ============ Kernel B: select + hybrid bitonic sort + chunked bitmask NMS (512 thr) ============
union ShMix2 {
  uint32_t rhist[512];                  // refine hist (2 KB)
  uint32_t fhist[FBBINS];               // fallback hist (8 KB)
  unsigned long long rowm[KPRE][4];     // IoU adjacency rows (8 KB)
};

__global__ __launch_bounds__(512) void select_nms_list_kernel(
    const unsigned long long* __restrict__ lists, const uint32_t* __restrict__ cnts,
    const uint32_t* __restrict__ ovfl, const float* __restrict__ boxes,
    const float* __restrict__ p5, const float* __restrict__ p4, const float* __restrict__ p3,
    float* __restrict__ kept_s, int* __restrict__ top_i)
{
  const int task = blockIdx.x;
  const int b = task / NCLS, c = task - b * NCLS;
  const int tid = threadIdx.x;

  __shared__ uint32_t S[256];
  __shared__ unsigned long long keys[GCAP];      // 4 KB
  __shared__ ShMix2 u;                           // 8 KB
  __shared__ float4 bbx[KPRE];                   // 4 KB
  __shared__ float bar_[KPRE];                   // 1 KB
  __shared__ unsigned long long suppInit[4];
  __shared__ unsigned long long sh_t[4];
  __shared__ int s_B, s_cnt, s_state, sh_stop;
  __shared__ float s_gl, s_lo, s_hi;
  __shared__ uint32_t s_above, s_g2;

  const uint32_t cntraw = cnts[(size_t)task * CSTR];
  bool fb = (ovfl[task] != 0u) || !(cntraw >= (uint32_t)KPRE && cntraw <= (uint32_t)LCAP);
  float thr = CUT;
  int n_all = (int)(cntraw < (uint32_t)LCAP ? cntraw : (uint32_t)LCAP);
  const unsigned long long* gl = lists + (size_t)task * LCAP;

  if (!fb && n_all > 500) {                      // small lists: gather-all, no hist needed
    if (tid < 256) S[tid] = 0;
    __syncthreads();
    for (int z = tid; z < n_all; z += 512) {
      float s = __uint_as_float((uint32_t)(gl[z] >> 32));
      int bin = (int)(__fmul_rn(__fsub_rn(s, CUT), HS2));
      bin = bin < 0 ? 0 : (bin > 255 ? 255 : bin);
      atomicAdd(&S[bin], 1u);
    }
    __syncthreads();
    for (int off = 1; off < 256; off <<= 1) {    // suffix scan: S[z] = count(bin >= z)
      uint32_t add = 0;
      if (tid < 256 && tid + off < 256) add = S[tid + off];
      __syncthreads();
      if (tid < 256) S[tid] += add;
      __syncthreads();
    }
    if (tid == 0) s_B = 0;
    __syncthreads();
    if (tid < 256) {
      uint32_t Sz = S[tid];
      uint32_t Sz1 = (tid < 255) ? S[tid + 1] : 0u;
      if (Sz >= KPRE && (tid == 255 || Sz1 < KPRE)) s_B = tid;
    }
    __syncthreads();
    const int B = s_B;
    const uint32_t gcount = S[B];
    const uint32_t aboveB = (B < 255) ? S[B + 1] : 0u;
    thr = CUT + (float)B * BINW;
    if (gcount > 500u) {
      for (int z = tid; z < 512; z += 512) u.rhist[z] = 0u;
      __syncthreads();
      float rLo = thr;
      for (int z = tid; z < n_all; z += 512) {
        float s = __uint_as_float((uint32_t)(gl[z] >> 32));
        int bin = (int)(__fmul_rn(__fsub_rn(s, CUT), HS2));
        bin = bin < 0 ? 0 : (bin > 255 ? 255 : bin);
        if (bin == B) {
          int sub = (int)((s - rLo) * RSC);
          sub = sub < 0 ? 0 : (sub > 511 ? 511 : sub);
          atomicAdd(&u.rhist[sub], 1u);
        }
      }
      __syncthreads();
      if (tid == 0) {
        uint32_t acc = aboveB; int B2 = 0;
        for (int z = 511; z >= 0; --z) {
          acc += u.rhist[z];
          if (acc >= KPRE) { B2 = z; break; }
        }
        s_gl = rLo + (float)B2 * (BINW / 512.0f);
        s_g2 = acc;
      }
      __syncthreads();
      thr = s_gl;
      if (s_g2 > 500u) fb = true;
      __syncthreads();
    }
  }

  if (fb) {
    // exact fallback: iterative strided hist over raw scores (never taken on bench data)
    float lo = SCORE_THR, hi = 1.0f;
    uint32_t above = 0;
    float gl2 = SCORE_THR;
    bool done = false;
    for (int iter = 0; iter < 6 && !done; ++iter) {
      for (int z = tid; z < FBBINS; z += 512) u.fhist[z] = 0u;
      __syncthreads();
      float scale = (float)FBBINS / (hi - lo);
      for (int i = tid; i < NBOX; i += 512) {
        float s = score_full(p5, p4, p3, b, c, i);
        if (s > lo && s <= hi) {
          int bin = (int)((s - lo) * scale);
          bin = bin < 0 ? 0 : (bin > FBBINS - 1 ? FBBINS - 1 : bin);
          atomicAdd(&u.fhist[bin], 1u);
        }
      }
      __syncthreads();
      if (tid < 256) {
        uint32_t cs = 0; int base = tid * 8;
        #pragma unroll
        for (int z = 0; z < 8; ++z) cs += u.fhist[base + z];
        S[tid] = cs;
      }
      __syncthreads();
      if (tid == 0) {
        uint32_t acc = 0; int ch;
        for (ch = 255; ch >= 0; --ch) {
          if (above + acc + S[ch] >= KPRE) break;
          acc += S[ch];
        }
        if (ch < 0) { s_state = 1; s_gl = SCORE_THR; }
        else {
          int B = -1;
          for (int z = ch * 8 + 7; z >= ch * 8; --z) {
            acc += u.fhist[z];
            if (above + acc >= KPRE) { B = z; break; }
          }
          uint32_t popB = u.fhist[B];
          uint32_t aboveNew = above + acc - popB;
          float wdt = (hi - lo) / (float)FBBINS;
          float binLo = lo + (float)B * wdt;
          if (aboveNew + popB <= 496u || iter == 5) { s_state = 1; s_gl = binLo; }
          else { s_state = 0; s_lo = binLo; s_hi = binLo + wdt; s_above = aboveNew; }
        }
      }
      __syncthreads();
      if (s_state == 1) { gl2 = s_gl; done = true; }
      else { lo = s_lo; hi = s_hi; above = s_above; }
      __syncthreads();
    }
    thr = gl2;
  }

  float thr_n = __uint_as_float(__float_as_uint(thr) - 8u);   // ulp nudge vs bin rounding

  if (tid == 0) s_cnt = 0;
  __syncthreads();
  if (!fb) {
    for (int z = tid; z < n_all; z += 512) {
      unsigned long long kk = gl[z];
      float s = __uint_as_float((uint32_t)(kk >> 32));
      if (s > thr_n) {
        int slot = atomicAdd(&s_cnt, 1);
        if (slot < GCAP) keys[slot] = kk;
      }
    }
  } else {
    for (int i = tid; i < NBOX; i += 512) {
      float s = score_full(p5, p4, p3, b, c, i);
      if (s > thr_n && s > SCORE_THR) {
        int slot = atomicAdd(&s_cnt, 1);
        if (slot < GCAP)
          keys[slot] = ((unsigned long long)__float_as_uint(s) << 32) | (0xFFFFFFFFu - (uint32_t)i);
      }
    }
  }
  __syncthreads();
  int n = s_cnt < GCAP ? s_cnt : GCAP;
  if (tid >= n) keys[tid] = 0ull;
  __syncthreads();
  // hybrid bitonic sort 512 descending: j<64 via register shfl_xor, j>=64 via LDS
  {
    unsigned long long v = keys[tid];
    for (int k = 2; k <= GCAP; k <<= 1) {
      for (int j = k >> 1; j > 0; j >>= 1) {
        unsigned long long pv;
        if (j >= 64) {
          keys[tid] = v;
          __syncthreads();
          pv = keys[tid ^ j];
          __syncthreads();
        } else {
          pv = __shfl_xor(v, j, 64);
        }
        bool takeMax = (((tid & k) == 0) == ((tid & j) == 0));
        v = takeMax ? (v > pv ? v : pv) : (v < pv ? v : pv);
      }
    }
    keys[tid] = v;
  }
  __syncthreads();

  // ---- chunked bitmask NMS on top-256 ----
  const int col = tid & 255;
  float sc; int idx;
  {
    unsigned long long kk = keys[col];
    if ((uint32_t)(kk >> 32) != 0u) { sc = __uint_as_float((uint32_t)(kk >> 32)); idx = (int)(0xFFFFFFFFu - (uint32_t)kk); }
    else { sc = -1.0f; idx = 0; }
  }
  if (tid < KPRE) {
    const float* bp = boxes + ((size_t)b * NBOX + idx) * 4;
    float bx1 = bp[0], by1 = bp[1], bx2 = bp[2], by2 = bp[3];
    bbx[tid] = make_float4(bx1, by1, bx2, by2);
    bar_[tid] = __fmul_rn(fmaxf(__fsub_rn(bx2, bx1), 0.0f), fmaxf(__fsub_rn(by2, by1), 0.0f));
  }
  {
    unsigned long long alive = __ballot(sc > SCORE_THR);
    if (tid < KPRE && (tid & 63) == 0) suppInit[tid >> 6] = ~alive;
  }
  if (tid == 0) sh_stop = 0;
  __syncthreads();
  float4 MB = bbx[col];
  float x1 = MB.x, y1 = MB.y, x2 = MB.z, y2 = MB.w;
  float area = bar_[col];
  if (tid < 4) sh_t[tid] = suppInit[tid];
  __syncthreads();

  int P = 4;
  const int rg = tid >> 8;                       // row-group: 0 or 1
  #pragma unroll
  for (int q = 0; q < 4; ++q) {
    for (int ii = 0; ii < 64; ii += 2) {
      int i = q * 64 + ii + rg;
      if (!((sh_t[q] >> (ii + rg)) & 1ull)) {
        float4 B = bbx[i];
        float ar = bar_[i];
        float iw = fmaxf(__fsub_rn(fminf(x2, B.z), fmaxf(x1, B.x)), 0.0f);
        float ih = fmaxf(__fsub_rn(fminf(y2, B.w), fmaxf(y1, B.y)), 0.0f);
        float inter = __fmul_rn(iw, ih);
        float ab = __fadd_rn(ar, area);
        float diff = __fsub_rn(__fmul_rn(inter, 1.1f), __fmul_rn(0.1f, ab));
        bool sup;
        if (fabsf(diff) > 1e-5f * ab) {
          sup = diff > 0.0f;
        } else {
          float uni = __fsub_rn(ab, inter);
          sup = (inter / fmaxf(uni, 1e-9f)) > IOU_THR;
        }
        sup = sup && (col > i);
        unsigned long long m = __ballot(sup);
        if ((tid & 63) == 0) u.rowm[i][(tid >> 6) & 3] = m;
      }
    }
    __syncthreads();
    if (tid == 0) {                              // serial greedy suppression for this chunk
      unsigned long long t0 = sh_t[0], t1 = sh_t[1], t2 = sh_t[2], t3 = sh_t[3];
      for (int ii = 0; ii < 64; ++ii) {
        int i = q * 64 + ii;
        unsigned long long cur = (q == 0) ? t0 : (q == 1) ? t1 : (q == 2) ? t2 : t3;
        if (!((cur >> ii) & 1ull)) {
          if (q <= 0) t0 |= u.rowm[i][0];
          if (q <= 1) t1 |= u.rowm[i][1];
          if (q <= 2) t2 |= u.rowm[i][2];
          t3 |= u.rowm[i][3];
        }
      }
      sh_t[0] = t0; sh_t[1] = t1; sh_t[2] = t2; sh_t[3] = t3;
      int kept = __popcll(~t0);
      if (q >= 1) kept += __popcll(~t1);
      if (q >= 2) kept += __popcll(~t2);
      if (q >= 3) kept += __popcll(~t3);
      if (kept >= MAXB) sh_stop = 1;             // rows beyond can't enter the top-100
    }
    __syncthreads();
    if (sh_stop) { P = q + 1; break; }
  }

  if (tid < KPRE) {
    unsigned long long tw = sh_t[tid >> 6];
    bool kept = (tid < 64 * P) && !((tw >> (tid & 63)) & 1ull);
    int rank = 0;
    #pragma unroll
    for (int w2 = 0; w2 < 4; ++w2)
      if (w2 < (tid >> 6)) rank += __popcll(~sh_t[w2]);
    int l = tid & 63;
    rank += (l == 0) ? 0 : __popcll(~tw & ((~0ull) >> (64 - l)));
    bool fin = kept && (rank < MAXB);
    kept_s[(size_t)task * KPRE + tid] = fin ? sc : -1.0f;
    top_i[(size_t)task * KPRE + tid] = idx;
  }
}

// ============ Small-ws fallback path (round-0/1, validated, 256 thr) ============
__global__ __launch_bounds__(256) void decode_kernel(
    const float* __restrict__ p5, const float* __restrict__ p4, const float* __restrict__ p3,
    float* __restrict__ boxes, float* __restrict__ conf)
{
  int t = blockIdx.x * 256 + threadIdx.x;
  if (t >= NIMG * NBOX) return;
  int b = t / NBOX, i = t - b * NBOX;
  const float* p; int g, li, abase;
  box_loc(i, p5, p4, p3, p, g, li, abase);
  int cell = li / 3, a = li - cell * 3;
  float ratio = 640.0f / (float)g;
  const float* f = p + ((size_t)((size_t)b * g * g + cell) * 255 + a * 85);
  float cx = (sigmoidf_(f[0]) + (float)(cell % g)) * ratio;
  float cy = (sigmoidf_(f[1]) + (float)(cell / g)) * ratio;
  float w = expf(f[2]) * c_AW[abase + a];
  float h = expf(f[3]) * c_AH[abase + a];
  float hw = 0.5f * w, hh = 0.5f * h;
  float* ob = boxes + (size_t)t * 4;
  ob[0] = cx - hw; ob[1] = cy - hh; ob[2] = cx + hw; ob[3] = cy + hh;
  conf[t] = sigmoidf_(f[4]);
}

__device__ __forceinline__ float score_at(
    const float* __restrict__ p5, const float* __restrict__ p4, const float* __restrict__ p3,
    const float* __restrict__ conf, int b, int c, int i)
{
  const float* p; int g, li, abase;
  box_loc(i, p5, p4, p3, p, g, li, abase);
  float logit = p[(size_t)((size_t)b * g * g * 3 + li) * 85 + 5 + c];
  return __fmul_rn(conf[b * NBOX + i], 1.0f / (1.0f + expf(-logit)));
}

__global__ __launch_bounds__(256) void select_nms_kernel(
    const float* __restrict__ p5, const float* __restrict__ p4, const float* __restrict__ p3,
    const float* __restrict__ conf, const float* __restrict__ boxes,
    float* __restrict__ kept_s, int* __restrict__ top_i)
{
  const int task = blockIdx.x;
  const int b = task / NCLS, c = task - b * NCLS;
  const int tid = threadIdx.x;
  __shared__ uint32_t hist[NBINS_OLD];
  __shared__ uint32_t chunkS[256];
  __shared__ unsigned long long keys[GCAP_OLD];
  __shared__ float s_lo, s_hi, s_glo;
  __shared__ uint32_t s_above;
  __shared__ int s_state, s_cnt;

  float lo = SCORE_THR, hi = 1.0f;
  uint32_t above = 0;
  float gatherLo = SCORE_THR;
  bool done = false;
  for (int iter = 0; iter < 6 && !done; ++iter) {
    for (int z = tid; z < NBINS_OLD; z += 256) hist[z] = 0;
    __syncthreads();
    float scale = (float)NBINS_OLD / (hi - lo);
    for (int i = tid; i < NBOX; i += 256) {
      float s = score_at(p5, p4, p3, conf, b, c, i);
      if (s > lo && s <= hi) {
        int bin = (int)((s - lo) * scale);
        bin = bin < 0 ? 0 : (bin > NBINS_OLD - 1 ? NBINS_OLD - 1 : bin);
        atomicAdd(&hist[bin], 1u);
      }
    }
    __syncthreads();
    { uint32_t cs = 0; int base = tid * 16;
      #pragma unroll
      for (int z = 0; z < 16; ++z) cs += hist[base + z];
      chunkS[tid] = cs; }
    __syncthreads();
    if (tid == 0) {
      uint32_t acc = 0; int ch;
      for (ch = 255; ch >= 0; --ch) {
        if (above + acc + chunkS[ch] >= KPRE) break;
        acc += chunkS[ch];
      }
      if (ch < 0) { s_state = 1; s_glo = SCORE_THR; }
      else {
        int B = -1;
        for (int z = ch * 16 + 15; z >= ch * 16; --z) {
          acc += hist[z];
          if (above + acc >= KPRE) { B = z; break; }
        }
        uint32_t popB = hist[B];
        uint32_t aboveNew = above + acc - popB;
        float wdt = (hi - lo) / (float)NBINS_OLD;
        float binLo = lo + (float)B * wdt;
        if (aboveNew + popB <= 1024u || iter == 5) { s_state = 1; s_glo = binLo; }
        else { s_state = 0; s_lo = binLo; s_hi = binLo + wdt; s_above = aboveNew; }
      }
    }
    __syncthreads();
    if (s_state == 1) { gatherLo = s_glo; done = true; }
    else { lo = s_lo; hi = s_hi; above = s_above; }
    __syncthreads();
  }
  gatherLo = __uint_as_float(__float_as_uint(gatherLo) - 8u);
  if (tid == 0) s_cnt = 0;
  __syncthreads();
  for (int i = tid; i < NBOX; i += 256) {
    float s = score_at(p5, p4, p3, conf, b, c, i);
    if (s > gatherLo && s > SCORE_THR) {
      int slot = atomicAdd(&s_cnt, 1);
      if (slot < GCAP_OLD)
        keys[slot] = ((unsigned long long)__float_as_uint(s) << 32) | (uint32_t)(0xFFFFFFFFu - (uint32_t)i);
    }
  }
  __syncthreads();
  int n = s_cnt < GCAP_OLD ? s_cnt : GCAP_OLD;
  for (int z = tid; z < GCAP_OLD; z += 256) if (z >= n) keys[z] = 0ull;
  __syncthreads();
  for (int k = 2; k <= GCAP_OLD; k <<= 1) {
    for (int j = k >> 1; j > 0; j >>= 1) {
      for (int i2 = tid; i2 < GCAP_OLD; i2 += 256) {
        int ixj = i2 ^ j;
        if (ixj > i2) {
          unsigned long long a0 = keys[i2], b0_ = keys[ixj];
          bool sw = ((i2 & k) == 0) ? (a0 < b0_) : (a0 > b0_);
          if (sw) { keys[i2] = b0_; keys[ixj] = a0; }
        }
      }
      __syncthreads();
    }
  }
  __shared__ float bx1[KPRE], by1[KPRE], bx2[KPRE], by2[KPRE], bar_[KPRE], tsc[KPRE];
  __shared__ int tix[KPRE];
  __shared__ unsigned char suppA[KPRE], keepA[KPRE];
  { int r = tid;
    unsigned long long kk = keys[r];
    float sc; int idx;
    if ((uint32_t)(kk >> 32) != 0u) { sc = __uint_as_float((uint32_t)(kk >> 32)); idx = (int)(0xFFFFFFFFu - (uint32_t)kk); }
    else { sc = -1.0f; idx = 0; }
    tsc[r] = sc; tix[r] = idx;
    const float* bp = boxes + ((size_t)b * NBOX + idx) * 4;
    float x1 = bp[0], y1 = bp[1], x2 = bp[2], y2 = bp[3];
    bx1[r] = x1; by1[r] = y1; bx2[r] = x2; by2[r] = y2;
    bar_[r] = __fmul_rn(fmaxf(__fsub_rn(x2, x1), 0.0f), fmaxf(__fsub_rn(y2, y1), 0.0f));
    suppA[r] = (sc <= SCORE_THR) ? 1 : 0; }
  __syncthreads();
  for (int i = 0; i < KPRE; ++i) {
    if (suppA[i] == 0) {
      int r = tid;
      if (r > i) {
        float iw = fmaxf(__fsub_rn(fminf(bx2[r], bx2[i]), fmaxf(bx1[r], bx1[i])), 0.0f);
        float ih = fmaxf(__fsub_rn(fminf(by2[r], by2[i]), fmaxf(by1[r], by1[i])), 0.0f);
        float inter = __fmul_rn(iw, ih);
        float uni = __fsub_rn(__fadd_rn(bar_[r], bar_[i]), inter);
        float iou = inter / fmaxf(uni, 1e-9f);
        if (iou > IOU_THR) suppA[r] = 1;
      }
    }
    __syncthreads();
  }
  if (tid == 0) {
    int cnt = 0;
    for (int r = 0; r < KPRE; ++r) {
      int kp = (suppA[r] == 0) ? 1 : 0;
      if (kp && cnt < MAXB) cnt++; else kp = 0;
      keepA[r] = (unsigned char)kp;
    }
  }
  __syncthreads();
  { int r = tid;
    kept_s[(size_t)task * KPRE + r] = keepA[r] ? tsc[r] : -1.0f;
    top_i[(size_t)task * KPRE + r] = tix[r]; }
}

// ============ Kernel C: per-image final top-100 (histogram select, small sort) ============
__global__ __launch_bounds__(256) void final_topk_kernel(
    const float* __restrict__ kept_s, const int* __restrict__ top_i,
    const float* __restrict__ boxes, float* __restrict__ out)
{
  int b = blockIdx.x, tid = threadIdx.x;
  __shared__ uint32_t hist[NBINS_OLD];
  __shared__ uint32_t chunkS[256];
  __shared__ unsigned long long keys[FK];
  __shared__ float s_lo, s_hi, s_glo;
  __shared__ uint32_t s_above;
  __shared__ int s_state, s_cnt;
  const float* ks = kept_s + (size_t)b * NCLS * KPRE;
  const int NK = NCLS * KPRE;

  float lo = SCORE_THR, hi = 1.0f;
  uint32_t above = 0;
  float gatherLo = SCORE_THR;
  bool done = false;

  for (int iter = 0; iter < 4 && !done; ++iter) {
    for (int z = tid; z < NBINS_OLD; z += 256) hist[z] = 0;
    __syncthreads();
    float scale = (float)NBINS_OLD / (hi - lo);
    for (int z = tid; z < NK; z += 256) {
      float s = ks[z];
      if (s > lo && s <= hi) {
        int bin = (int)((s - lo) * scale);
        bin = bin < 0 ? 0 : (bin > NBINS_OLD - 1 ? NBINS_OLD - 1 : bin);
        atomicAdd(&hist[bin], 1u);
      }
    }
    __syncthreads();
    {
      uint32_t cs = 0; int base = tid * 16;
      #pragma unroll
      for (int z = 0; z < 16; ++z) cs += hist[base + z];
      chunkS[tid] = cs;
    }
    __syncthreads();
    if (tid == 0) {
      uint32_t acc = 0; int ch;
      for (ch = 255; ch >= 0; --ch) {
        if (above + acc + chunkS[ch] >= MAXB) break;
        acc += chunkS[ch];
      }
      if (ch < 0) { s_state = 1; s_glo = SCORE_THR; }
      else {
        int B = -1;
        for (int z = ch * 16 + 15; z >= ch * 16; --z) {
          acc += hist[z];
          if (above + acc >= MAXB) { B = z; break; }
        }
        uint32_t popB = hist[B];
        uint32_t aboveNew = above + acc - popB;
        float wdt = (hi - lo) / (float)NBINS_OLD;
        float binLo = lo + (float)B * wdt;
        if (aboveNew + popB <= (uint32_t)(FK - 64) || iter == 3) { s_state = 1; s_glo = binLo; }
        else { s_state = 0; s_lo = binLo; s_hi = binLo + wdt; s_above = aboveNew; }
      }
    }
    __syncthreads();
    if (s_state == 1) { gatherLo = s_glo; done = true; }
    else { lo = s_lo; hi = s_hi; above = s_above; }
    __syncthreads();
  }
  gatherLo = __uint_as_float(__float_as_uint(gatherLo) - 8u);

  if (tid == 0) s_cnt = 0;
  __syncthreads();
  for (int z = tid; z < NK; z += 256) {
    float s = ks[z];
    if (s > gatherLo && s > 0.0f) {
      int slot = atomicAdd(&s_cnt, 1);
      if (slot < FK)
        keys[slot] = ((unsigned long long)__float_as_uint(s) << 32) | (uint32_t)(0xFFFFFFFFu - (uint32_t)z);
    }
  }
  __syncthreads();
  int n = s_cnt < FK ? s_cnt : FK;
  for (int z = tid; z < FK; z += 256) if (z >= n) keys[z] = 0ull;
  __syncthreads();
  for (int k = 2; k <= FK; k <<= 1) {
    for (int j = k >> 1; j > 0; j >>= 1) {
      for (int i2 = tid; i2 < FK; i2 += 256) {
        int ixj = i2 ^ j;
        if (ixj > i2) {
          unsigned long long a0 = keys[i2], b0_ = keys[ixj];
          bool sw = ((i2 & k) == 0) ? (a0 < b0_) : (a0 > b0_);
          if (sw) { keys[i2] = b0_; keys[ixj] = a0; }
        }
      }
      __syncthreads();
    }
  }
  float* ob = out + (size_t)b * MAXB * 4;
  float* os = out + (size_t)NIMG * MAXB * 4 + (size_t)b * MAXB;
  float* ol = out + (size_t)NIMG * MAXB * 4 + (size_t)NIMG * MAXB + (size_t)b * MAXB;
  for (int t = tid; t < MAXB; t += 256) {
    unsigned long long kk = keys[t];
    if ((uint32_t)(kk >> 32) != 0u) {
      float s = __uint_as_float((uint32_t)(kk >> 32));
      int fr = (int)(0xFFFFFFFFu - (uint32_t)kk);
      int cc = fr >> 8, rr = fr & 255;
      int idx = top_i[((size_t)b * NCLS + cc) * KPRE + rr];
      const float* bp = boxes + ((size_t)b * NBOX + idx) * 4;
      ob[t * 4 + 0] = bp[0]; ob[t * 4 + 1] = bp[1]; ob[t * 4 + 2] = bp[2]; ob[t * 4 + 3] = bp[3];
      os[t] = s; ol[t] = (float)cc;
    } else {
      ob[t * 4 + 0] = -1.0f; ob[t * 4 + 1] = -1.0f; ob[t * 4 + 2] = -1.0f; ob[t * 4 + 3] = -1.0f;
      os[t] = -1.0f; ol[t] = -1.0f;
    }
  }
}

extern "C" void kernel_launch(void* const* d_in, const int* in_sizes, int n_in,
                              void* d_out, int out_size, void* d_ws, size_t ws_size,
                              hipStream_t stream)
{
  const float* p5 = (const float*)d_in[0];
  const float* p4 = (const float*)d_in[1];
  const float* p3 = (const float*)d_in[2];
  float* out = (float*)d_out;

  float*    boxes = (float*)d_ws;                                    // 403200*4 f
  float*    kept  = boxes + (size_t)NIMG * NBOX * 4;                 // 1280*256 f
  int*      topi  = (int*)(kept + (size_t)NIMG * NCLS * KPRE);       // 1280*256 i
  uint32_t* cnts  = (uint32_t*)(topi + (size_t)NIMG * NCLS * KPRE);  // 1280*16 u32 (line-padded)
  uint32_t* ovfl  = cnts + (size_t)NIMG * NCLS * CSTR;               // 1280 u32
  unsigned long long* lists = (unsigned long long*)(ovfl + NIMG * NCLS); // 1280*3072 u64

  size_t need_main = ((size_t)NIMG * NBOX * 4 + (size_t)NIMG * NCLS * KPRE * 2
                      + (size_t)NIMG * NCLS * CSTR + (size_t)NIMG * NCLS) * 4
                     + (size_t)NIMG * NCLS * LCAP * 8;

  if (ws_size >= need_main) {
    hipMemsetAsync(cnts, 0, (size_t)NIMG * NCLS * (CSTR + 1) * sizeof(uint32_t), stream);
    decode_push_kernel<<<NIMG * BPI, 512, 0, stream>>>(p5, p4, p3, boxes, lists, cnts, ovfl);
    select_nms_list_kernel<<<NIMG * NCLS, 512, 0, stream>>>(lists, cnts, ovfl, boxes, p5, p4, p3, kept, topi);
  } else {
    float* conf = (float*)(cnts);                                    // reuse tail: 403200 f
    decode_kernel<<<(NIMG * NBOX + 255) / 256, 256, 0, stream>>>(p5, p4, p3, boxes, conf);
    select_nms_kernel<<<NIMG * NCLS, 256, 0, stream>>>(p5, p4, p3, conf, boxes, kept, topi);
  }
  final_topk_kernel<<<NIMG, 256, 0, stream>>>(kept, topi, boxes, out);
}